// Round 2
// baseline (2185.593 us; speedup 1.0000x reference)
//
#include <hip/hip_runtime.h>
#include <hip/hip_bf16.h>

// Problem constants (match reference)
#define DM    1024   // D_MODEL
#define DI    2048   // D_INNER
#define DCONV 4
#define DSTATE 16
#define DRANK 64
#define BB    4
#define LSEQ  2048
#define MM    (BB*LSEQ)   // 8192 rows
#define CHUNK 64          // scan LDS-staging chunk (timesteps)

// ---------------------------------------------------------------------------
// GEMM NT: C[M][N] = A[M][K] * B[N][K]^T   (both row-major, K contiguous)
// 128x128 tile, BK=16, 256 threads, 8x8 per thread (4+4 split fragments:
// cols {tx*4..+3} u {64+tx*4..+3}, rows likewise -> 2-way LDS conflicts only,
// and perfectly coalesced 256B C-store segments per 16 lanes).
// ---------------------------------------------------------------------------
__global__ __launch_bounds__(256) void gemm_nt(
    float* __restrict__ C, const float* __restrict__ A, const float* __restrict__ B,
    int M, int N, int K)
{
    __shared__ float As[16][132];   // [k][m], 132*4B=528B rows keep 16B alignment
    __shared__ float Bs[16][132];   // [k][n]

    const int tid = threadIdx.x;
    const int m0 = blockIdx.y * 128;
    const int n0 = blockIdx.x * 128;
    const int tx = tid & 15;        // 16 thread-cols
    const int ty = tid >> 4;        // 16 thread-rows
    const int lrow = tid >> 2;      // loader: 0..63
    const int lc4  = tid & 3;       // loader: 0..3 (BK/4)

    float acc[8][8] = {};

    for (int k0 = 0; k0 < K; k0 += 16) {
#pragma unroll
        for (int r = 0; r < 2; ++r) {
            const int row = lrow + r * 64;
            const float4 va = *(const float4*)&A[(size_t)(m0 + row) * K + k0 + lc4 * 4];
            As[lc4*4+0][row] = va.x; As[lc4*4+1][row] = va.y;
            As[lc4*4+2][row] = va.z; As[lc4*4+3][row] = va.w;
            const float4 vb = *(const float4*)&B[(size_t)(n0 + row) * K + k0 + lc4 * 4];
            Bs[lc4*4+0][row] = vb.x; Bs[lc4*4+1][row] = vb.y;
            Bs[lc4*4+2][row] = vb.z; Bs[lc4*4+3][row] = vb.w;
        }
        __syncthreads();
#pragma unroll
        for (int kk = 0; kk < 16; ++kk) {
            const float4 a0 = *(const float4*)&As[kk][ty * 4];
            const float4 a1 = *(const float4*)&As[kk][64 + ty * 4];
            const float4 b0 = *(const float4*)&Bs[kk][tx * 4];
            const float4 b1 = *(const float4*)&Bs[kk][64 + tx * 4];
            const float a[8] = {a0.x, a0.y, a0.z, a0.w, a1.x, a1.y, a1.z, a1.w};
            const float b[8] = {b0.x, b0.y, b0.z, b0.w, b1.x, b1.y, b1.z, b1.w};
#pragma unroll
            for (int i = 0; i < 8; ++i)
#pragma unroll
                for (int j = 0; j < 8; ++j)
                    acc[i][j] = fmaf(a[i], b[j], acc[i][j]);
        }
        __syncthreads();
    }

#pragma unroll
    for (int i = 0; i < 8; ++i) {
        const int row = m0 + ((i < 4) ? (ty * 4 + i) : (64 + ty * 4 + i - 4));
        const float4 o0 = {acc[i][0], acc[i][1], acc[i][2], acc[i][3]};
        const float4 o1 = {acc[i][4], acc[i][5], acc[i][6], acc[i][7]};
        float* cp = &C[(size_t)row * N + n0];
        *(float4*)(cp + tx * 4)      = o0;
        *(float4*)(cp + 64 + tx * 4) = o1;
    }
}

// ---------------------------------------------------------------------------
// Depthwise causal conv (width 4) + bias + SiLU.  xi [M][DI] -> xc [M][DI]
// ---------------------------------------------------------------------------
__global__ __launch_bounds__(256) void conv_silu_kernel(
    const float* __restrict__ xi, const float* __restrict__ cw,
    const float* __restrict__ cb, float* __restrict__ xc)
{
    const int idx = blockIdx.x * 256 + threadIdx.x;   // over MM*DI/4
    const int d4 = idx & (DI / 4 - 1);
    const int bl = idx / (DI / 4);
    const int l  = bl & (LSEQ - 1);
    const int d  = d4 * 4;

    float4 acc = *(const float4*)&cb[d];
    const float4 w0 = *(const float4*)&cw[(d + 0) * 4];
    const float4 w1 = *(const float4*)&cw[(d + 1) * 4];
    const float4 w2 = *(const float4*)&cw[(d + 2) * 4];
    const float4 w3 = *(const float4*)&cw[(d + 3) * 4];

#pragma unroll
    for (int k = 0; k < 4; ++k) {
        const int ll = l - 3 + k;
        if (ll < 0) continue;
        const float4 xv = *(const float4*)&xi[(size_t)(bl - 3 + k) * DI + d];
        const float wk0 = (k == 0) ? w0.x : (k == 1) ? w0.y : (k == 2) ? w0.z : w0.w;
        const float wk1 = (k == 0) ? w1.x : (k == 1) ? w1.y : (k == 2) ? w1.z : w1.w;
        const float wk2 = (k == 0) ? w2.x : (k == 1) ? w2.y : (k == 2) ? w2.z : w2.w;
        const float wk3 = (k == 0) ? w3.x : (k == 1) ? w3.y : (k == 2) ? w3.z : w3.w;
        acc.x = fmaf(xv.x, wk0, acc.x);
        acc.y = fmaf(xv.y, wk1, acc.y);
        acc.z = fmaf(xv.z, wk2, acc.z);
        acc.w = fmaf(xv.w, wk3, acc.w);
    }
    acc.x = acc.x / (1.f + __expf(-acc.x));
    acc.y = acc.y / (1.f + __expf(-acc.y));
    acc.z = acc.z / (1.f + __expf(-acc.z));
    acc.w = acc.w / (1.f + __expf(-acc.w));
    *(float4*)&xc[(size_t)bl * DI + d] = acc;
}

// ---------------------------------------------------------------------------
// xdbl[M][96] = xc[M][2048] * W_x[96][2048]^T
// ---------------------------------------------------------------------------
__global__ __launch_bounds__(256) void xdbl_kernel(
    const float* __restrict__ xc, const float* __restrict__ Wx, float* __restrict__ xdbl)
{
    __shared__ float s[16][256];
    const int t = threadIdx.x;
    const int m0 = blockIdx.x * 16;
    float acc[16] = {};

    for (int kc = 0; kc < DI; kc += 256) {
        __syncthreads();
#pragma unroll
        for (int r = 0; r < 4; ++r) {
            const int id = t + 256 * r;       // 1024 float4 total
            const int row = id >> 6, c4 = id & 63;
            *(float4*)&s[row][c4 * 4] =
                *(const float4*)&xc[(size_t)(m0 + row) * DI + kc + c4 * 4];
        }
        __syncthreads();
        if (t < 96) {
            for (int k4 = 0; k4 < 64; ++k4) {
                const float4 w4 = *(const float4*)&Wx[(size_t)t * DI + kc + k4 * 4];
#pragma unroll
                for (int i = 0; i < 16; ++i) {
                    acc[i] += s[i][k4*4+0] * w4.x + s[i][k4*4+1] * w4.y
                            + s[i][k4*4+2] * w4.z + s[i][k4*4+3] * w4.w;
                }
            }
        }
    }
    if (t < 96) {
#pragma unroll
        for (int i = 0; i < 16; ++i)
            xdbl[(size_t)(m0 + i) * 96 + t] = acc[i];
    }
}

// ---------------------------------------------------------------------------
// dt[M][DI] = softplus(dt_lo[M][64] * W_dt[DI][64]^T + b_dt)
// ---------------------------------------------------------------------------
__global__ __launch_bounds__(256) void dt_kernel(
    const float* __restrict__ xdbl, const float* __restrict__ Wdt,
    const float* __restrict__ bdt, float* __restrict__ dt)
{
    __shared__ float s[16][64];
    const int t = threadIdx.x;
    const int m0 = blockIdx.y * 16;

    {   // stage dt_lo: 16 rows x 64 = 256 float4, one per thread
        const int row = t >> 4, c4 = t & 15;
        *(float4*)&s[row][c4 * 4] =
            *(const float4*)&xdbl[(size_t)(m0 + row) * 96 + c4 * 4];
    }
    __syncthreads();

    const int n = blockIdx.x * 256 + t;
    float4 w[16];
#pragma unroll
    for (int k4 = 0; k4 < 16; ++k4)
        w[k4] = *(const float4*)&Wdt[(size_t)n * 64 + k4 * 4];
    const float bd = bdt[n];

#pragma unroll
    for (int i = 0; i < 16; ++i) {
        float acc = bd;
#pragma unroll
        for (int k4 = 0; k4 < 16; ++k4) {
            acc += s[i][k4*4+0] * w[k4].x + s[i][k4*4+1] * w[k4].y
                 + s[i][k4*4+2] * w[k4].z + s[i][k4*4+3] * w[k4].w;
        }
        const float sp = (acc > 20.f) ? acc : log1pf(__expf(acc));
        dt[(size_t)(m0 + i) * DI + n] = sp;
    }
}

// ---------------------------------------------------------------------------
// Selective scan with chunked LDS staging.
// Block: 256 threads = 16 channel-groups x 16 states. 16 channels per block.
// Per 64-step chunk: cooperative coalesced load of (dt,xc,z,B,C) -> regs ->
// LDS, compute 64 steps from LDS (broadcast reads), y buffered back through
// s_z and stored coalesced. Next chunk's global loads are issued before the
// compute loop so ~500-900cy latency hides under ~2300cy of compute.
// y is written IN-PLACE over z (same thread covers the same float4: global
// read of z[chunk c] is issued a full chunk before the y store to the same
// addresses, ordered through the LDS/barrier dependence chain).
// ---------------------------------------------------------------------------
__global__ __launch_bounds__(256) void scan_kernel(
    const float* __restrict__ dt, const float* __restrict__ xc,
    const float* __restrict__ xdbl, const float* z,
    const float* __restrict__ A_log, const float* __restrict__ D_skip,
    float* y)
{
    __shared__ float s_dt[CHUNK][16];
    __shared__ float s_xc[CHUNK][16];
    __shared__ float s_z [CHUNK][16];   // z in, y out
    __shared__ float s_B [CHUNK][16];
    __shared__ float s_C [CHUNK][16];

    const int t = threadIdx.x;
    const int g = t >> 4;             // channel group in block, 0..15
    const int s = t & 15;             // state index
    const int c = blockIdx.x * 16 + g;       // global channel
    const int b = c >> 11;                   // / DI  (block never straddles b)
    const int d = c & (DI - 1);
    const int d0 = (blockIdx.x * 16) & (DI - 1);

    const int lr = t >> 2;            // loader row 0..63
    const int lc = t & 3;             // loader float4-col 0..3

    const float Acoef = -__expf(A_log[d * DSTATE + s]);
    const float Dv = D_skip[d];
    const size_t rbase = (size_t)b * LSEQ;

    float h = 0.f;
    float4 r_dt, r_xc, r_z, r_B, r_C;

    // prologue: load chunk 0 into regs
    {
        const size_t row = rbase + lr;
        r_dt = *(const float4*)&dt[row * DI + d0 + lc * 4];
        r_xc = *(const float4*)&xc[row * DI + d0 + lc * 4];
        r_z  = *(const float4*)&z [row * DI + d0 + lc * 4];
        r_B  = *(const float4*)&xdbl[row * 96 + DRANK + lc * 4];
        r_C  = *(const float4*)&xdbl[row * 96 + DRANK + DSTATE + lc * 4];
    }

    for (int ch = 0; ch < LSEQ / CHUNK; ++ch) {
        __syncthreads();              // prev chunk's LDS fully consumed/stored
        *(float4*)&s_dt[lr][lc * 4] = r_dt;
        *(float4*)&s_xc[lr][lc * 4] = r_xc;
        *(float4*)&s_z [lr][lc * 4] = r_z;
        *(float4*)&s_B [lr][lc * 4] = r_B;
        *(float4*)&s_C [lr][lc * 4] = r_C;
        __syncthreads();

        if (ch + 1 < LSEQ / CHUNK) {  // issue next chunk's loads (in flight)
            const size_t row = rbase + (size_t)(ch + 1) * CHUNK + lr;
            r_dt = *(const float4*)&dt[row * DI + d0 + lc * 4];
            r_xc = *(const float4*)&xc[row * DI + d0 + lc * 4];
            r_z  = *(const float4*)&z [row * DI + d0 + lc * 4];
            r_B  = *(const float4*)&xdbl[row * 96 + DRANK + lc * 4];
            r_C  = *(const float4*)&xdbl[row * 96 + DRANK + DSTATE + lc * 4];
        }

        for (int j = 0; j < CHUNK; ++j) {
            const float dtv = s_dt[j][g];        // broadcast within group
            const float xv  = s_xc[j][g];
            const float Bv  = s_B[j][s];
            const float Cv  = s_C[j][s];
            const float dA = __expf(dtv * Acoef);
            h = fmaf(dA, h, dtv * xv * Bv);
            float p = h * Cv;
            p += __shfl_xor(p, 1);
            p += __shfl_xor(p, 2);
            p += __shfl_xor(p, 4);
            p += __shfl_xor(p, 8);
            if (s == 0) {
                const float zv = s_z[j][g];
                const float sig = 1.f / (1.f + __expf(-zv));
                s_z[j][g] = fmaf(xv, Dv, p) * (zv * sig);   // y into s_z
            }
        }
        __syncthreads();
        // coalesced y chunk store (in-place over z)
        {
            const size_t row = rbase + (size_t)ch * CHUNK + lr;
            *(float4*)&y[row * DI + d0 + lc * 4] = *(const float4*)&s_z[lr][lc * 4];
        }
    }
}

// ---------------------------------------------------------------------------
extern "C" void kernel_launch(void* const* d_in, const int* in_sizes, int n_in,
                              void* d_out, int out_size, void* d_ws, size_t ws_size,
                              hipStream_t stream)
{
    const float* x      = (const float*)d_in[0];
    const float* W_in   = (const float*)d_in[1];
    const float* cw     = (const float*)d_in[2];
    const float* cb     = (const float*)d_in[3];
    const float* W_x    = (const float*)d_in[4];
    const float* W_dt   = (const float*)d_in[5];
    const float* b_dt   = (const float*)d_in[6];
    const float* A_log  = (const float*)d_in[7];
    const float* D_skip = (const float*)d_in[8];
    const float* W_out  = (const float*)d_in[9];
    float* out = (float*)d_out;

    // Workspace layout (floats), 195 MB total:
    //   xi  : MM*DI  (xi, then reused for dt)
    //   zb  : MM*DI  (z, then y written in-place by scan)
    //   xcb : MM*DI
    //   xdb : MM*96
    float* xi  = (float*)d_ws;
    float* zb  = xi  + (size_t)MM * DI;
    float* xcb = zb  + (size_t)MM * DI;
    float* xdb = xcb + (size_t)MM * DI;

    const dim3 blk(256);

    // xz = x @ W_in^T, xi / z halves
    gemm_nt<<<dim3(DI / 128, MM / 128), blk, 0, stream>>>(xi, x, W_in, MM, DI, DM);
    gemm_nt<<<dim3(DI / 128, MM / 128), blk, 0, stream>>>(
        zb, x, W_in + (size_t)DI * DM, MM, DI, DM);

    conv_silu_kernel<<<dim3(MM * (DI / 4) / 256), blk, 0, stream>>>(xi, cw, cb, xcb);

    xdbl_kernel<<<dim3(MM / 16), blk, 0, stream>>>(xcb, W_x, xdb);

    dt_kernel<<<dim3(DI / 256, MM / 16), blk, 0, stream>>>(xdb, W_dt, b_dt, xi);

    scan_kernel<<<dim3(BB * DI / 16), blk, 0, stream>>>(
        xi, xcb, xdb, zb, A_log, D_skip, zb);

    gemm_nt<<<dim3(DM / 128, MM / 128), blk, 0, stream>>>(out, zb, W_out, MM, DM, DI);
}

// Round 3
// 1747.636 us; speedup vs baseline: 1.2506x; 1.2506x over previous
//
#include <hip/hip_runtime.h>
#include <hip/hip_bf16.h>

// Problem constants (match reference)
#define DM    1024   // D_MODEL
#define DI    2048   // D_INNER
#define DCONV 4
#define DSTATE 16
#define DRANK 64
#define BB    4
#define LSEQ  2048
#define MM    (BB*LSEQ)   // 8192 rows
#define CHUNK 64          // scan LDS-staging chunk (timesteps)

// ---------------------------------------------------------------------------
// GEMM NT: C[M][N] = A[M][K] * B[N][K]^T   (both row-major, K contiguous)
// 128x128 tile, BK=16, 256 threads, 8x8 per thread (4+4 split fragments).
// ---------------------------------------------------------------------------
__global__ __launch_bounds__(256) void gemm_nt(
    float* __restrict__ C, const float* __restrict__ A, const float* __restrict__ B,
    int M, int N, int K)
{
    __shared__ float As[16][132];   // [k][m]
    __shared__ float Bs[16][132];   // [k][n]

    const int tid = threadIdx.x;
    const int m0 = blockIdx.y * 128;
    const int n0 = blockIdx.x * 128;
    const int tx = tid & 15;        // 16 thread-cols
    const int ty = tid >> 4;        // 16 thread-rows
    const int lrow = tid >> 2;      // loader: 0..63
    const int lc4  = tid & 3;       // loader: 0..3 (BK/4)

    float acc[8][8] = {};

    for (int k0 = 0; k0 < K; k0 += 16) {
#pragma unroll
        for (int r = 0; r < 2; ++r) {
            const int row = lrow + r * 64;
            const float4 va = *(const float4*)&A[(size_t)(m0 + row) * K + k0 + lc4 * 4];
            As[lc4*4+0][row] = va.x; As[lc4*4+1][row] = va.y;
            As[lc4*4+2][row] = va.z; As[lc4*4+3][row] = va.w;
            const float4 vb = *(const float4*)&B[(size_t)(n0 + row) * K + k0 + lc4 * 4];
            Bs[lc4*4+0][row] = vb.x; Bs[lc4*4+1][row] = vb.y;
            Bs[lc4*4+2][row] = vb.z; Bs[lc4*4+3][row] = vb.w;
        }
        __syncthreads();
#pragma unroll
        for (int kk = 0; kk < 16; ++kk) {
            const float4 a0 = *(const float4*)&As[kk][ty * 4];
            const float4 a1 = *(const float4*)&As[kk][64 + ty * 4];
            const float4 b0 = *(const float4*)&Bs[kk][tx * 4];
            const float4 b1 = *(const float4*)&Bs[kk][64 + tx * 4];
            const float a[8] = {a0.x, a0.y, a0.z, a0.w, a1.x, a1.y, a1.z, a1.w};
            const float b[8] = {b0.x, b0.y, b0.z, b0.w, b1.x, b1.y, b1.z, b1.w};
#pragma unroll
            for (int i = 0; i < 8; ++i)
#pragma unroll
                for (int j = 0; j < 8; ++j)
                    acc[i][j] = fmaf(a[i], b[j], acc[i][j]);
        }
        __syncthreads();
    }

#pragma unroll
    for (int i = 0; i < 8; ++i) {
        const int row = m0 + ((i < 4) ? (ty * 4 + i) : (64 + ty * 4 + i - 4));
        const float4 o0 = {acc[i][0], acc[i][1], acc[i][2], acc[i][3]};
        const float4 o1 = {acc[i][4], acc[i][5], acc[i][6], acc[i][7]};
        float* cp = &C[(size_t)row * N + n0];
        *(float4*)(cp + tx * 4)      = o0;
        *(float4*)(cp + 64 + tx * 4) = o1;
    }
}

// ---------------------------------------------------------------------------
// Depthwise causal conv (width 4) + bias + SiLU.  xi [M][DI] -> xc [M][DI]
// ---------------------------------------------------------------------------
__global__ __launch_bounds__(256) void conv_silu_kernel(
    const float* __restrict__ xi, const float* __restrict__ cw,
    const float* __restrict__ cb, float* __restrict__ xc)
{
    const int idx = blockIdx.x * 256 + threadIdx.x;   // over MM*DI/4
    const int d4 = idx & (DI / 4 - 1);
    const int bl = idx / (DI / 4);
    const int l  = bl & (LSEQ - 1);
    const int d  = d4 * 4;

    float4 acc = *(const float4*)&cb[d];
    const float4 w0 = *(const float4*)&cw[(d + 0) * 4];
    const float4 w1 = *(const float4*)&cw[(d + 1) * 4];
    const float4 w2 = *(const float4*)&cw[(d + 2) * 4];
    const float4 w3 = *(const float4*)&cw[(d + 3) * 4];

#pragma unroll
    for (int k = 0; k < 4; ++k) {
        const int ll = l - 3 + k;
        if (ll < 0) continue;
        const float4 xv = *(const float4*)&xi[(size_t)(bl - 3 + k) * DI + d];
        const float wk0 = (k == 0) ? w0.x : (k == 1) ? w0.y : (k == 2) ? w0.z : w0.w;
        const float wk1 = (k == 0) ? w1.x : (k == 1) ? w1.y : (k == 2) ? w1.z : w1.w;
        const float wk2 = (k == 0) ? w2.x : (k == 1) ? w2.y : (k == 2) ? w2.z : w2.w;
        const float wk3 = (k == 0) ? w3.x : (k == 1) ? w3.y : (k == 2) ? w3.z : w3.w;
        acc.x = fmaf(xv.x, wk0, acc.x);
        acc.y = fmaf(xv.y, wk1, acc.y);
        acc.z = fmaf(xv.z, wk2, acc.z);
        acc.w = fmaf(xv.w, wk3, acc.w);
    }
    acc.x = acc.x / (1.f + __expf(-acc.x));
    acc.y = acc.y / (1.f + __expf(-acc.y));
    acc.z = acc.z / (1.f + __expf(-acc.z));
    acc.w = acc.w / (1.f + __expf(-acc.w));
    *(float4*)&xc[(size_t)bl * DI + d] = acc;
}

// ---------------------------------------------------------------------------
// xdbl[M][96] = xc[M][2048] * W_x[96][2048]^T
// ---------------------------------------------------------------------------
__global__ __launch_bounds__(256) void xdbl_kernel(
    const float* __restrict__ xc, const float* __restrict__ Wx, float* __restrict__ xdbl)
{
    __shared__ float s[16][256];
    const int t = threadIdx.x;
    const int m0 = blockIdx.x * 16;
    float acc[16] = {};

    for (int kc = 0; kc < DI; kc += 256) {
        __syncthreads();
#pragma unroll
        for (int r = 0; r < 4; ++r) {
            const int id = t + 256 * r;       // 1024 float4 total
            const int row = id >> 6, c4 = id & 63;
            *(float4*)&s[row][c4 * 4] =
                *(const float4*)&xc[(size_t)(m0 + row) * DI + kc + c4 * 4];
        }
        __syncthreads();
        if (t < 96) {
            for (int k4 = 0; k4 < 64; ++k4) {
                const float4 w4 = *(const float4*)&Wx[(size_t)t * DI + kc + k4 * 4];
#pragma unroll
                for (int i = 0; i < 16; ++i) {
                    acc[i] += s[i][k4*4+0] * w4.x + s[i][k4*4+1] * w4.y
                            + s[i][k4*4+2] * w4.z + s[i][k4*4+3] * w4.w;
                }
            }
        }
    }
    if (t < 96) {
#pragma unroll
        for (int i = 0; i < 16; ++i)
            xdbl[(size_t)(m0 + i) * 96 + t] = acc[i];
    }
}

// ---------------------------------------------------------------------------
// dt[M][DI] = softplus(dt_lo[M][64] * W_dt[DI][64]^T + b_dt)
// ---------------------------------------------------------------------------
__global__ __launch_bounds__(256) void dt_kernel(
    const float* __restrict__ xdbl, const float* __restrict__ Wdt,
    const float* __restrict__ bdt, float* __restrict__ dt)
{
    __shared__ float s[16][64];
    const int t = threadIdx.x;
    const int m0 = blockIdx.y * 16;

    {   // stage dt_lo: 16 rows x 64 = 256 float4, one per thread
        const int row = t >> 4, c4 = t & 15;
        *(float4*)&s[row][c4 * 4] =
            *(const float4*)&xdbl[(size_t)(m0 + row) * 96 + c4 * 4];
    }
    __syncthreads();

    const int n = blockIdx.x * 256 + t;
    float4 w[16];
#pragma unroll
    for (int k4 = 0; k4 < 16; ++k4)
        w[k4] = *(const float4*)&Wdt[(size_t)n * 64 + k4 * 4];
    const float bd = bdt[n];

#pragma unroll
    for (int i = 0; i < 16; ++i) {
        float acc = bd;
#pragma unroll
        for (int k4 = 0; k4 < 16; ++k4) {
            acc += s[i][k4*4+0] * w[k4].x + s[i][k4*4+1] * w[k4].y
                 + s[i][k4*4+2] * w[k4].z + s[i][k4*4+3] * w[k4].w;
        }
        const float sp = (acc > 20.f) ? acc : log1pf(__expf(acc));
        dt[(size_t)(m0 + i) * DI + n] = sp;
    }
}

// ---------------------------------------------------------------------------
// Selective scan, phase-batched (no per-step cross-lane ops).
// Block: 256 threads = 16 channels (g) x 16 states (s). Chunk = 64 steps.
// Per 16-step sub-chunk:
//   scan phase : lane (g,s) computes 16 indep exps + the 16-FMA h chain,
//                writes p = h*C to wave-private s_p[g][j][s] (pad 17 -> 2-way).
//   reduce     : after barrier, thread (g,j) sums s_p[g][j][0..15]
//                (verified <=2-way banks), applies D_skip + silu(z),
//                writes y into s_z[base+j][g].
// y is written IN-PLACE over z (same-thread program order + barriers give the
// needed read-before-write ordering).
// ---------------------------------------------------------------------------
__global__ __launch_bounds__(256) void scan_kernel(
    const float* __restrict__ dt, const float* __restrict__ xc,
    const float* __restrict__ xdbl, const float* z,
    const float* __restrict__ A_log, const float* __restrict__ D_skip,
    float* y)
{
    __shared__ float s_dt[CHUNK][16];
    __shared__ float s_xc[CHUNK][16];
    __shared__ float s_z [CHUNK][16];   // z in, y out
    __shared__ float s_B [CHUNK][16];
    __shared__ float s_C [CHUNK][16];
    __shared__ float s_p [16][16][17];  // [g][j][s] pad 17
    __shared__ float s_D [16];

    const int t = threadIdx.x;
    const int g = t >> 4;             // channel in block, 0..15
    const int s = t & 15;             // state index
    const int c = blockIdx.x * 16 + g;       // global channel
    const int b = c >> 11;                   // / DI  (block never straddles b)
    const int d = c & (DI - 1);
    const int d0 = (blockIdx.x * 16) & (DI - 1);

    const int lr = t >> 2;            // loader row 0..63
    const int lc = t & 3;             // loader float4-col 0..3

    if (t < 16) s_D[t] = D_skip[d0 + t];

    const float Acoef = -__expf(A_log[d * DSTATE + s]);
    const size_t rbase = (size_t)b * LSEQ;

    float h = 0.f;
    float4 r_dt, r_xc, r_z, r_B, r_C;

    {   // prologue: chunk 0 -> regs
        const size_t row = rbase + lr;
        r_dt = *(const float4*)&dt[row * DI + d0 + lc * 4];
        r_xc = *(const float4*)&xc[row * DI + d0 + lc * 4];
        r_z  = *(const float4*)&z [row * DI + d0 + lc * 4];
        r_B  = *(const float4*)&xdbl[row * 96 + DRANK + lc * 4];
        r_C  = *(const float4*)&xdbl[row * 96 + DRANK + DSTATE + lc * 4];
    }

    for (int ch = 0; ch < LSEQ / CHUNK; ++ch) {
        __syncthreads();              // prev chunk's LDS fully consumed/stored
        *(float4*)&s_dt[lr][lc * 4] = r_dt;
        *(float4*)&s_xc[lr][lc * 4] = r_xc;
        *(float4*)&s_z [lr][lc * 4] = r_z;
        *(float4*)&s_B [lr][lc * 4] = r_B;
        *(float4*)&s_C [lr][lc * 4] = r_C;
        __syncthreads();

        if (ch + 1 < LSEQ / CHUNK) {  // issue next chunk's loads (stay in flight)
            const size_t row = rbase + (size_t)(ch + 1) * CHUNK + lr;
            r_dt = *(const float4*)&dt[row * DI + d0 + lc * 4];
            r_xc = *(const float4*)&xc[row * DI + d0 + lc * 4];
            r_z  = *(const float4*)&z [row * DI + d0 + lc * 4];
            r_B  = *(const float4*)&xdbl[row * 96 + DRANK + lc * 4];
            r_C  = *(const float4*)&xdbl[row * 96 + DRANK + DSTATE + lc * 4];
        }

#pragma unroll
        for (int sub = 0; sub < CHUNK / 16; ++sub) {
            const int base = sub * 16;
            // ---- scan phase: batched, independent except the 16-FMA h chain
            float dA[16], u[16], Cv[16];
#pragma unroll
            for (int j = 0; j < 16; ++j) {
                const float dtv = s_dt[base + j][g];   // 4-addr broadcast
                const float xv  = s_xc[base + j][g];
                const float Bv  = s_B [base + j][s];
                Cv[j] = s_C[base + j][s];
                dA[j] = __expf(dtv * Acoef);
                u[j]  = dtv * xv * Bv;
            }
#pragma unroll
            for (int j = 0; j < 16; ++j) {
                h = fmaf(dA[j], h, u[j]);
                s_p[g][j][s] = h * Cv[j];              // 2-way banks: free
            }
            __syncthreads();
            // ---- reduce phase: thread (g, j=s) finalizes step base+s of chan g
            float accp = 0.f;
#pragma unroll
            for (int k = 0; k < 16; ++k)
                accp += s_p[g][s][k];                  // <=2-way banks
            {
                const int row = base + s;
                const float xv = s_xc[row][g];
                const float zv = s_z [row][g];
                const float sig = 1.f / (1.f + __expf(-zv));
                s_z[row][g] = fmaf(xv, s_D[g], accp) * (zv * sig);
            }
            __syncthreads();
        }
        // coalesced y chunk store (in-place over z)
        {
            const size_t row = rbase + (size_t)ch * CHUNK + lr;
            *(float4*)&y[row * DI + d0 + lc * 4] = *(const float4*)&s_z[lr][lc * 4];
        }
    }
}

// ---------------------------------------------------------------------------
extern "C" void kernel_launch(void* const* d_in, const int* in_sizes, int n_in,
                              void* d_out, int out_size, void* d_ws, size_t ws_size,
                              hipStream_t stream)
{
    const float* x      = (const float*)d_in[0];
    const float* W_in   = (const float*)d_in[1];
    const float* cw     = (const float*)d_in[2];
    const float* cb     = (const float*)d_in[3];
    const float* W_x    = (const float*)d_in[4];
    const float* W_dt   = (const float*)d_in[5];
    const float* b_dt   = (const float*)d_in[6];
    const float* A_log  = (const float*)d_in[7];
    const float* D_skip = (const float*)d_in[8];
    const float* W_out  = (const float*)d_in[9];
    float* out = (float*)d_out;

    // Workspace layout (floats), 195 MB total:
    //   xi  : MM*DI  (xi, then reused for dt)
    //   zb  : MM*DI  (z, then y written in-place by scan)
    //   xcb : MM*DI
    //   xdb : MM*96
    float* xi  = (float*)d_ws;
    float* zb  = xi  + (size_t)MM * DI;
    float* xcb = zb  + (size_t)MM * DI;
    float* xdb = xcb + (size_t)MM * DI;

    const dim3 blk(256);

    // xz = x @ W_in^T, xi / z halves
    gemm_nt<<<dim3(DI / 128, MM / 128), blk, 0, stream>>>(xi, x, W_in, MM, DI, DM);
    gemm_nt<<<dim3(DI / 128, MM / 128), blk, 0, stream>>>(
        zb, x, W_in + (size_t)DI * DM, MM, DI, DM);

    conv_silu_kernel<<<dim3(MM * (DI / 4) / 256), blk, 0, stream>>>(xi, cw, cb, xcb);

    xdbl_kernel<<<dim3(MM / 16), blk, 0, stream>>>(xcb, W_x, xdb);

    dt_kernel<<<dim3(DI / 256, MM / 16), blk, 0, stream>>>(xdb, W_dt, b_dt, xi);

    scan_kernel<<<dim3(BB * DI / 16), blk, 0, stream>>>(
        xi, xcb, xdb, zb, A_log, D_skip, zb);

    gemm_nt<<<dim3(DM / 128, MM / 128), blk, 0, stream>>>(out, zb, W_out, MM, DM, DI);
}

// Round 5
// 989.854 us; speedup vs baseline: 2.2080x; 1.7655x over previous
//
#include <hip/hip_runtime.h>
#include <hip/hip_bf16.h>

// Problem constants (match reference)
#define DM    1024   // D_MODEL
#define DI    2048   // D_INNER
#define DCONV 4
#define DSTATE 16
#define DRANK 64
#define BB    4
#define LSEQ  2048
#define MM    (BB*LSEQ)   // 8192 rows
#define CHUNK 64          // scan LDS-staging chunk (timesteps)

typedef _Float16 f16x8 __attribute__((ext_vector_type(8)));
typedef float    f32x4 __attribute__((ext_vector_type(4)));

// LDS swizzle: 16B slot index within a 64B row, XORed so 16-row column reads
// are 2-way (free) on 32 banks. Verified by bank enumeration (see notes).
#define SWIZ(row, g) ((((row) * 4) + ((g) ^ ((row) & 3) ^ (((row) >> 2) & 1))) * 8)

// ---------------------------------------------------------------------------
// split: fp32 -> (hi, lo) f16 pair.  lo = f16(x - float(hi)); x==hi+lo+O(2^-22)
// ---------------------------------------------------------------------------
__global__ __launch_bounds__(256) void split_kernel(
    const float* __restrict__ in, _Float16* __restrict__ hi,
    _Float16* __restrict__ lo, int n4)
{
    const int i = blockIdx.x * 256 + threadIdx.x;
    if (i >= n4) return;
    const float4 v = ((const float4*)in)[i];
    _Float16 h[4], l[4];
    h[0] = (_Float16)v.x; l[0] = (_Float16)(v.x - (float)h[0]);
    h[1] = (_Float16)v.y; l[1] = (_Float16)(v.y - (float)h[1]);
    h[2] = (_Float16)v.z; l[2] = (_Float16)(v.z - (float)h[2]);
    h[3] = (_Float16)v.w; l[3] = (_Float16)(v.w - (float)h[3]);
    *(uint2*)&hi[(size_t)i * 4] = *(uint2*)h;
    *(uint2*)&lo[(size_t)i * 4] = *(uint2*)l;
}

// ---------------------------------------------------------------------------
// Split-precision MFMA GEMM NT:
//   C[M][N] (fp32) = (Ah+Al)[M][K] * ((Bh+Bl)[N][K])^T
// via 3 products Ah*Bh + Ah*Bl + Al*Bh on mfma_f32_16x16x32_f16.
// 128x128 tile, BK=32, 256 threads = 4 waves (2x2 of 64x64), 4x4 16x16 frags
// per wave. Reg-staged LDS (XOR-swizzled), next-tile global loads issued
// before the MFMA section so HBM latency hides under compute.
// ---------------------------------------------------------------------------
__global__ __launch_bounds__(256) void gemm_nt_split(
    float* __restrict__ C,
    const _Float16* __restrict__ Ah, const _Float16* __restrict__ Al,
    const _Float16* __restrict__ Bh, const _Float16* __restrict__ Bl,
    int M, int N, int K)
{
    __shared__ __align__(16) _Float16 sAh[128 * 32];
    __shared__ __align__(16) _Float16 sAl[128 * 32];
    __shared__ __align__(16) _Float16 sBh[128 * 32];
    __shared__ __align__(16) _Float16 sBl[128 * 32];

    const int t = threadIdx.x;
    const int m0 = blockIdx.y * 128, n0 = blockIdx.x * 128;
    const int l = t & 63, w = t >> 6;
    const int wr = w >> 1, wc = w & 1;          // wave quadrant (2x2 of 64x64)
    const int fr = l & 15, fg = l >> 4;         // frag row/col + k-group

    f32x4 acc[4][4];
    const f32x4 zz = {0.f, 0.f, 0.f, 0.f};
#pragma unroll
    for (int i = 0; i < 4; ++i)
#pragma unroll
        for (int j = 0; j < 4; ++j) acc[i][j] = zz;

    // staging: 2 16B slots per thread per array; slot s -> row s>>2, col4 s&3
    const int r0 = t >> 2, c0 = t & 3;
    const int r1 = r0 + 64, c1 = c0;
    const int d0 = SWIZ(r0, c0), d1 = SWIZ(r1, c1);
    const size_t gA0 = (size_t)(m0 + r0) * K + c0 * 8;
    const size_t gA1 = (size_t)(m0 + r1) * K + c1 * 8;
    const size_t gB0 = (size_t)(n0 + r0) * K + c0 * 8;
    const size_t gB1 = (size_t)(n0 + r1) * K + c1 * 8;

    uint4 vAh0 = *(const uint4*)&Ah[gA0], vAh1 = *(const uint4*)&Ah[gA1];
    uint4 vAl0 = *(const uint4*)&Al[gA0], vAl1 = *(const uint4*)&Al[gA1];
    uint4 vBh0 = *(const uint4*)&Bh[gB0], vBh1 = *(const uint4*)&Bh[gB1];
    uint4 vBl0 = *(const uint4*)&Bl[gB0], vBl1 = *(const uint4*)&Bl[gB1];

    const int nk = K / 32;
    for (int kt = 0; kt < nk; ++kt) {
        __syncthreads();                     // prev iter's frag reads done
        *(uint4*)&sAh[d0] = vAh0;  *(uint4*)&sAh[d1] = vAh1;
        *(uint4*)&sAl[d0] = vAl0;  *(uint4*)&sAl[d1] = vAl1;
        *(uint4*)&sBh[d0] = vBh0;  *(uint4*)&sBh[d1] = vBh1;
        *(uint4*)&sBl[d0] = vBl0;  *(uint4*)&sBl[d1] = vBl1;
        __syncthreads();

        if (kt + 1 < nk) {                   // issue next tile (stays in flight)
            const size_t o = (size_t)(kt + 1) * 32;
            vAh0 = *(const uint4*)&Ah[gA0 + o]; vAh1 = *(const uint4*)&Ah[gA1 + o];
            vAl0 = *(const uint4*)&Al[gA0 + o]; vAl1 = *(const uint4*)&Al[gA1 + o];
            vBh0 = *(const uint4*)&Bh[gB0 + o]; vBh1 = *(const uint4*)&Bh[gB1 + o];
            vBl0 = *(const uint4*)&Bl[gB0 + o]; vBl1 = *(const uint4*)&Bl[gB1 + o];
        }

        // B fragments (held in regs), A fragments read per-mr
        f16x8 fbh[4], fbl[4];
#pragma unroll
        for (int nr = 0; nr < 4; ++nr) {
            const int row = wc * 64 + nr * 16 + fr;
            const int ad = SWIZ(row, fg);
            fbh[nr] = *(const f16x8*)&sBh[ad];
            fbl[nr] = *(const f16x8*)&sBl[ad];
        }
#pragma unroll
        for (int mr = 0; mr < 4; ++mr) {
            const int row = wr * 64 + mr * 16 + fr;
            const int ad = SWIZ(row, fg);
            const f16x8 fah = *(const f16x8*)&sAh[ad];
            const f16x8 fal = *(const f16x8*)&sAl[ad];
#pragma unroll
            for (int nr = 0; nr < 4; ++nr) {
                acc[mr][nr] = __builtin_amdgcn_mfma_f32_16x16x32_f16(
                    fah, fbh[nr], acc[mr][nr], 0, 0, 0);
                acc[mr][nr] = __builtin_amdgcn_mfma_f32_16x16x32_f16(
                    fah, fbl[nr], acc[mr][nr], 0, 0, 0);
                acc[mr][nr] = __builtin_amdgcn_mfma_f32_16x16x32_f16(
                    fal, fbh[nr], acc[mr][nr], 0, 0, 0);
            }
        }
    }

    // epilogue: verified C/D layout col=lane&15, row=(lane>>4)*4+reg
#pragma unroll
    for (int mr = 0; mr < 4; ++mr)
#pragma unroll
        for (int nr = 0; nr < 4; ++nr) {
            const int col = n0 + wc * 64 + nr * 16 + fr;
#pragma unroll
            for (int q = 0; q < 4; ++q) {
                const int rowc = m0 + wr * 64 + mr * 16 + fg * 4 + q;
                C[(size_t)rowc * N + col] = acc[mr][nr][q];
            }
        }
}

// ---------------------------------------------------------------------------
// Depthwise causal conv (width 4) + bias + SiLU.  xi [M][DI] -> xc [M][DI]
// ---------------------------------------------------------------------------
__global__ __launch_bounds__(256) void conv_silu_kernel(
    const float* __restrict__ xi, const float* __restrict__ cw,
    const float* __restrict__ cb, float* __restrict__ xc)
{
    const int idx = blockIdx.x * 256 + threadIdx.x;   // over MM*DI/4
    const int d4 = idx & (DI / 4 - 1);
    const int bl = idx / (DI / 4);
    const int l  = bl & (LSEQ - 1);
    const int d  = d4 * 4;

    float4 acc = *(const float4*)&cb[d];
    const float4 w0 = *(const float4*)&cw[(d + 0) * 4];
    const float4 w1 = *(const float4*)&cw[(d + 1) * 4];
    const float4 w2 = *(const float4*)&cw[(d + 2) * 4];
    const float4 w3 = *(const float4*)&cw[(d + 3) * 4];

#pragma unroll
    for (int k = 0; k < 4; ++k) {
        const int ll = l - 3 + k;
        if (ll < 0) continue;
        const float4 xv = *(const float4*)&xi[(size_t)(bl - 3 + k) * DI + d];
        const float wk0 = (k == 0) ? w0.x : (k == 1) ? w0.y : (k == 2) ? w0.z : w0.w;
        const float wk1 = (k == 0) ? w1.x : (k == 1) ? w1.y : (k == 2) ? w1.z : w1.w;
        const float wk2 = (k == 0) ? w2.x : (k == 1) ? w2.y : (k == 2) ? w2.z : w2.w;
        const float wk3 = (k == 0) ? w3.x : (k == 1) ? w3.y : (k == 2) ? w3.z : w3.w;
        acc.x = fmaf(xv.x, wk0, acc.x);
        acc.y = fmaf(xv.y, wk1, acc.y);
        acc.z = fmaf(xv.z, wk2, acc.z);
        acc.w = fmaf(xv.w, wk3, acc.w);
    }
    acc.x = acc.x / (1.f + __expf(-acc.x));
    acc.y = acc.y / (1.f + __expf(-acc.y));
    acc.z = acc.z / (1.f + __expf(-acc.z));
    acc.w = acc.w / (1.f + __expf(-acc.w));
    *(float4*)&xc[(size_t)bl * DI + d] = acc;
}

// ---------------------------------------------------------------------------
// xdbl[M][96] = xc[M][2048] * W_x[96][2048]^T
// ---------------------------------------------------------------------------
__global__ __launch_bounds__(256) void xdbl_kernel(
    const float* __restrict__ xc, const float* __restrict__ Wx, float* __restrict__ xdbl)
{
    __shared__ float s[16][256];
    const int t = threadIdx.x;
    const int m0 = blockIdx.x * 16;
    float acc[16] = {};

    for (int kc = 0; kc < DI; kc += 256) {
        __syncthreads();
#pragma unroll
        for (int r = 0; r < 4; ++r) {
            const int id = t + 256 * r;       // 1024 float4 total
            const int row = id >> 6, c4 = id & 63;
            *(float4*)&s[row][c4 * 4] =
                *(const float4*)&xc[(size_t)(m0 + row) * DI + kc + c4 * 4];
        }
        __syncthreads();
        if (t < 96) {
            for (int k4 = 0; k4 < 64; ++k4) {
                const float4 w4 = *(const float4*)&Wx[(size_t)t * DI + kc + k4 * 4];
#pragma unroll
                for (int i = 0; i < 16; ++i) {
                    acc[i] += s[i][k4*4+0] * w4.x + s[i][k4*4+1] * w4.y
                            + s[i][k4*4+2] * w4.z + s[i][k4*4+3] * w4.w;
                }
            }
        }
    }
    if (t < 96) {
#pragma unroll
        for (int i = 0; i < 16; ++i)
            xdbl[(size_t)(m0 + i) * 96 + t] = acc[i];
    }
}

// ---------------------------------------------------------------------------
// dt[M][DI] = softplus(dt_lo[M][64] * W_dt[DI][64]^T + b_dt)
// ---------------------------------------------------------------------------
__global__ __launch_bounds__(256) void dt_kernel(
    const float* __restrict__ xdbl, const float* __restrict__ Wdt,
    const float* __restrict__ bdt, float* __restrict__ dt)
{
    __shared__ float s[16][64];
    const int t = threadIdx.x;
    const int m0 = blockIdx.y * 16;

    {   // stage dt_lo: 16 rows x 64 = 256 float4, one per thread
        const int row = t >> 4, c4 = t & 15;
        *(float4*)&s[row][c4 * 4] =
            *(const float4*)&xdbl[(size_t)(m0 + row) * 96 + c4 * 4];
    }
    __syncthreads();

    const int n = blockIdx.x * 256 + t;
    float4 w[16];
#pragma unroll
    for (int k4 = 0; k4 < 16; ++k4)
        w[k4] = *(const float4*)&Wdt[(size_t)n * 64 + k4 * 4];
    const float bd = bdt[n];

#pragma unroll
    for (int i = 0; i < 16; ++i) {
        float acc = bd;
#pragma unroll
        for (int k4 = 0; k4 < 16; ++k4) {
            acc += s[i][k4*4+0] * w[k4].x + s[i][k4*4+1] * w[k4].y
                 + s[i][k4*4+2] * w[k4].z + s[i][k4*4+3] * w[k4].w;
        }
        const float sp = (acc > 20.f) ? acc : log1pf(__expf(acc));
        dt[(size_t)(m0 + i) * DI + n] = sp;
    }
}

// ---------------------------------------------------------------------------
// Selective scan, phase-batched (no per-step cross-lane ops). See round-3.
// ---------------------------------------------------------------------------
__global__ __launch_bounds__(256) void scan_kernel(
    const float* __restrict__ dt, const float* __restrict__ xc,
    const float* __restrict__ xdbl, const float* z,
    const float* __restrict__ A_log, const float* __restrict__ D_skip,
    float* y)
{
    __shared__ float s_dt[CHUNK][16];
    __shared__ float s_xc[CHUNK][16];
    __shared__ float s_z [CHUNK][16];   // z in, y out
    __shared__ float s_B [CHUNK][16];
    __shared__ float s_C [CHUNK][16];
    __shared__ float s_p [16][16][17];  // [g][j][s] pad 17
    __shared__ float s_D [16];

    const int t = threadIdx.x;
    const int g = t >> 4;             // channel in block, 0..15
    const int s = t & 15;             // state index
    const int c = blockIdx.x * 16 + g;       // global channel
    const int b = c >> 11;                   // / DI  (block never straddles b)
    const int d = c & (DI - 1);
    const int d0 = (blockIdx.x * 16) & (DI - 1);

    const int lr = t >> 2;            // loader row 0..63
    const int lc = t & 3;             // loader float4-col 0..3

    if (t < 16) s_D[t] = D_skip[d0 + t];

    const float Acoef = -__expf(A_log[d * DSTATE + s]);
    const size_t rbase = (size_t)b * LSEQ;

    float h = 0.f;
    float4 r_dt, r_xc, r_z, r_B, r_C;

    {   // prologue: chunk 0 -> regs
        const size_t row = rbase + lr;
        r_dt = *(const float4*)&dt[row * DI + d0 + lc * 4];
        r_xc = *(const float4*)&xc[row * DI + d0 + lc * 4];
        r_z  = *(const float4*)&z [row * DI + d0 + lc * 4];
        r_B  = *(const float4*)&xdbl[row * 96 + DRANK + lc * 4];
        r_C  = *(const float4*)&xdbl[row * 96 + DRANK + DSTATE + lc * 4];
    }

    for (int ch = 0; ch < LSEQ / CHUNK; ++ch) {
        __syncthreads();              // prev chunk's LDS fully consumed/stored
        *(float4*)&s_dt[lr][lc * 4] = r_dt;
        *(float4*)&s_xc[lr][lc * 4] = r_xc;
        *(float4*)&s_z [lr][lc * 4] = r_z;
        *(float4*)&s_B [lr][lc * 4] = r_B;
        *(float4*)&s_C [lr][lc * 4] = r_C;
        __syncthreads();

        if (ch + 1 < LSEQ / CHUNK) {  // issue next chunk's loads (stay in flight)
            const size_t row = rbase + (size_t)(ch + 1) * CHUNK + lr;
            r_dt = *(const float4*)&dt[row * DI + d0 + lc * 4];
            r_xc = *(const float4*)&xc[row * DI + d0 + lc * 4];
            r_z  = *(const float4*)&z [row * DI + d0 + lc * 4];
            r_B  = *(const float4*)&xdbl[row * 96 + DRANK + lc * 4];
            r_C  = *(const float4*)&xdbl[row * 96 + DRANK + DSTATE + lc * 4];
        }

#pragma unroll
        for (int sub = 0; sub < CHUNK / 16; ++sub) {
            const int base = sub * 16;
            // ---- scan phase: batched, independent except the 16-FMA h chain
            float dA[16], u[16], Cv[16];
#pragma unroll
            for (int j = 0; j < 16; ++j) {
                const float dtv = s_dt[base + j][g];   // 4-addr broadcast
                const float xv  = s_xc[base + j][g];
                const float Bv  = s_B [base + j][s];
                Cv[j] = s_C[base + j][s];
                dA[j] = __expf(dtv * Acoef);
                u[j]  = dtv * xv * Bv;
            }
#pragma unroll
            for (int j = 0; j < 16; ++j) {
                h = fmaf(dA[j], h, u[j]);
                s_p[g][j][s] = h * Cv[j];              // 2-way banks: free
            }
            __syncthreads();
            // ---- reduce phase: thread (g, j=s) finalizes step base+s of chan g
            float accp = 0.f;
#pragma unroll
            for (int k = 0; k < 16; ++k)
                accp += s_p[g][s][k];                  // <=2-way banks
            {
                const int row = base + s;
                const float xv = s_xc[row][g];
                const float zv = s_z [row][g];
                const float sig = 1.f / (1.f + __expf(-zv));
                s_z[row][g] = fmaf(xv, s_D[g], accp) * (zv * sig);
            }
            __syncthreads();
        }
        // coalesced y chunk store (in-place over z)
        {
            const size_t row = rbase + (size_t)ch * CHUNK + lr;
            *(float4*)&y[row * DI + d0 + lc * 4] = *(const float4*)&s_z[lr][lc * 4];
        }
    }
}

// ---------------------------------------------------------------------------
extern "C" void kernel_launch(void* const* d_in, const int* in_sizes, int n_in,
                              void* d_out, int out_size, void* d_ws, size_t ws_size,
                              hipStream_t stream)
{
    const float* x      = (const float*)d_in[0];
    const float* W_in   = (const float*)d_in[1];
    const float* cw     = (const float*)d_in[2];
    const float* cb     = (const float*)d_in[3];
    const float* W_x    = (const float*)d_in[4];
    const float* W_dt   = (const float*)d_in[5];
    const float* b_dt   = (const float*)d_in[6];
    const float* A_log  = (const float*)d_in[7];
    const float* D_skip = (const float*)d_in[8];
    const float* W_out  = (const float*)d_in[9];
    float* out = (float*)d_out;

    // fp32 workspace (identical 205MB footprint to rounds 2/3):
    const size_t MMDI = (size_t)MM * DI;
    float* xi  = (float*)d_ws;          // xz-half -> (dead) -> dt -> Wout-split
    float* zb  = xi  + MMDI;            // z -> y (in-place)
    float* xcb = zb  + MMDI;            // x/Win splits -> xc -> y splits
    float* xdb = xcb + MMDI;            // MM*96

    // f16 aliases (all inside dead fp32 regions at their time of use)
    _Float16* xh   = (_Float16*)xcb;                 // MM*DM
    _Float16* xl   = xh + (size_t)MM * DM;
    _Float16* Winh = xl + (size_t)MM * DM;           // 2*DI*DM
    _Float16* Winl = Winh + (size_t)2 * DI * DM;     // ends 25.2M of 33.5M halves
    _Float16* yh   = (_Float16*)xcb;                 // MM*DI (after scan)
    _Float16* yl   = yh + MMDI;
    _Float16* Woh  = (_Float16*)xi;                  // DM*DI (after scan)
    _Float16* Wol  = Woh + (size_t)DM * DI;

    const dim3 blk(256);

    // split inputs of GEMM1
    split_kernel<<<dim3((MM * DM / 4) / 256), blk, 0, stream>>>(x, xh, xl, MM * DM / 4);
    split_kernel<<<dim3((2 * DI * DM / 4) / 256), blk, 0, stream>>>(
        W_in, Winh, Winl, 2 * DI * DM / 4);

    // xz = x @ W_in^T, xi / z halves (MFMA split GEMM)
    gemm_nt_split<<<dim3(DI / 128, MM / 128), blk, 0, stream>>>(
        xi, xh, xl, Winh, Winl, MM, DI, DM);
    gemm_nt_split<<<dim3(DI / 128, MM / 128), blk, 0, stream>>>(
        zb, xh, xl, Winh + (size_t)DI * DM, Winl + (size_t)DI * DM, MM, DI, DM);

    // conv overwrites xcb (x/Win splits dead now)
    conv_silu_kernel<<<dim3(MM * (DI / 4) / 256), blk, 0, stream>>>(xi, cw, cb, xcb);

    xdbl_kernel<<<dim3(MM / 16), blk, 0, stream>>>(xcb, W_x, xdb);

    dt_kernel<<<dim3(DI / 256, MM / 16), blk, 0, stream>>>(xdb, W_dt, b_dt, xi);

    scan_kernel<<<dim3(BB * DI / 16), blk, 0, stream>>>(
        xi, xcb, xdb, zb, A_log, D_skip, zb);

    // split GEMM4 inputs into now-dead regions
    split_kernel<<<dim3((MM * DI / 4) / 256), blk, 0, stream>>>(zb, yh, yl, MM * DI / 4);
    split_kernel<<<dim3((DM * DI / 4) / 256), blk, 0, stream>>>(
        W_out, Woh, Wol, DM * DI / 4);

    gemm_nt_split<<<dim3(DM / 128, MM / 128), blk, 0, stream>>>(
        out, yh, yl, Woh, Wol, MM, DM, DI);
}

// Round 6
// 827.280 us; speedup vs baseline: 2.6419x; 1.1965x over previous
//
#include <hip/hip_runtime.h>
#include <hip/hip_bf16.h>

// Problem constants (match reference)
#define DM    1024   // D_MODEL
#define DI    2048   // D_INNER
#define DCONV 4
#define DSTATE 16
#define DRANK 64
#define BB    4
#define LSEQ  2048
#define MM    (BB*LSEQ)   // 8192 rows
#define CHUNK 64          // scan LDS-staging chunk (timesteps)

typedef _Float16 f16x8 __attribute__((ext_vector_type(8)));
typedef _Float16 f16x4 __attribute__((ext_vector_type(4)));
typedef float    f32x4 __attribute__((ext_vector_type(4)));

// LDS swizzle: 16B slot index within a 64B row, XORed so 16-row column reads
// are 2-way (free) on 32 banks.
#define SWIZ(row, g) ((((row) * 4) + ((g) ^ ((row) & 3) ^ (((row) >> 2) & 1))) * 8)

// ---------------------------------------------------------------------------
// split: fp32 -> (hi, lo) f16 pair.  lo = f16(x - float(hi)); x==hi+lo+O(2^-22)
// ---------------------------------------------------------------------------
__global__ __launch_bounds__(256) void split_kernel(
    const float* __restrict__ in, _Float16* __restrict__ hi,
    _Float16* __restrict__ lo, int n4)
{
    const int i = blockIdx.x * 256 + threadIdx.x;
    if (i >= n4) return;
    const float4 v = ((const float4*)in)[i];
    _Float16 h[4], l[4];
    h[0] = (_Float16)v.x; l[0] = (_Float16)(v.x - (float)h[0]);
    h[1] = (_Float16)v.y; l[1] = (_Float16)(v.y - (float)h[1]);
    h[2] = (_Float16)v.z; l[2] = (_Float16)(v.z - (float)h[2]);
    h[3] = (_Float16)v.w; l[3] = (_Float16)(v.w - (float)h[3]);
    *(uint2*)&hi[(size_t)i * 4] = *(uint2*)h;
    *(uint2*)&lo[(size_t)i * 4] = *(uint2*)l;
}

// ---------------------------------------------------------------------------
// Split-precision MFMA GEMM NT (unchanged from round 4).
// ---------------------------------------------------------------------------
__global__ __launch_bounds__(256) void gemm_nt_split(
    float* __restrict__ C,
    const _Float16* __restrict__ Ah, const _Float16* __restrict__ Al,
    const _Float16* __restrict__ Bh, const _Float16* __restrict__ Bl,
    int M, int N, int K)
{
    __shared__ __align__(16) _Float16 sAh[128 * 32];
    __shared__ __align__(16) _Float16 sAl[128 * 32];
    __shared__ __align__(16) _Float16 sBh[128 * 32];
    __shared__ __align__(16) _Float16 sBl[128 * 32];

    const int t = threadIdx.x;
    const int m0 = blockIdx.y * 128, n0 = blockIdx.x * 128;
    const int l = t & 63, w = t >> 6;
    const int wr = w >> 1, wc = w & 1;
    const int fr = l & 15, fg = l >> 4;

    f32x4 acc[4][4];
    const f32x4 zz = {0.f, 0.f, 0.f, 0.f};
#pragma unroll
    for (int i = 0; i < 4; ++i)
#pragma unroll
        for (int j = 0; j < 4; ++j) acc[i][j] = zz;

    const int r0 = t >> 2, c0 = t & 3;
    const int r1 = r0 + 64, c1 = c0;
    const int d0 = SWIZ(r0, c0), d1 = SWIZ(r1, c1);
    const size_t gA0 = (size_t)(m0 + r0) * K + c0 * 8;
    const size_t gA1 = (size_t)(m0 + r1) * K + c1 * 8;
    const size_t gB0 = (size_t)(n0 + r0) * K + c0 * 8;
    const size_t gB1 = (size_t)(n0 + r1) * K + c1 * 8;

    uint4 vAh0 = *(const uint4*)&Ah[gA0], vAh1 = *(const uint4*)&Ah[gA1];
    uint4 vAl0 = *(const uint4*)&Al[gA0], vAl1 = *(const uint4*)&Al[gA1];
    uint4 vBh0 = *(const uint4*)&Bh[gB0], vBh1 = *(const uint4*)&Bh[gB1];
    uint4 vBl0 = *(const uint4*)&Bl[gB0], vBl1 = *(const uint4*)&Bl[gB1];

    const int nk = K / 32;
    for (int kt = 0; kt < nk; ++kt) {
        __syncthreads();
        *(uint4*)&sAh[d0] = vAh0;  *(uint4*)&sAh[d1] = vAh1;
        *(uint4*)&sAl[d0] = vAl0;  *(uint4*)&sAl[d1] = vAl1;
        *(uint4*)&sBh[d0] = vBh0;  *(uint4*)&sBh[d1] = vBh1;
        *(uint4*)&sBl[d0] = vBl0;  *(uint4*)&sBl[d1] = vBl1;
        __syncthreads();

        if (kt + 1 < nk) {
            const size_t o = (size_t)(kt + 1) * 32;
            vAh0 = *(const uint4*)&Ah[gA0 + o]; vAh1 = *(const uint4*)&Ah[gA1 + o];
            vAl0 = *(const uint4*)&Al[gA0 + o]; vAl1 = *(const uint4*)&Al[gA1 + o];
            vBh0 = *(const uint4*)&Bh[gB0 + o]; vBh1 = *(const uint4*)&Bh[gB1 + o];
            vBl0 = *(const uint4*)&Bl[gB0 + o]; vBl1 = *(const uint4*)&Bl[gB1 + o];
        }

        f16x8 fbh[4], fbl[4];
#pragma unroll
        for (int nr = 0; nr < 4; ++nr) {
            const int row = wc * 64 + nr * 16 + fr;
            const int ad = SWIZ(row, fg);
            fbh[nr] = *(const f16x8*)&sBh[ad];
            fbl[nr] = *(const f16x8*)&sBl[ad];
        }
#pragma unroll
        for (int mr = 0; mr < 4; ++mr) {
            const int row = wr * 64 + mr * 16 + fr;
            const int ad = SWIZ(row, fg);
            const f16x8 fah = *(const f16x8*)&sAh[ad];
            const f16x8 fal = *(const f16x8*)&sAl[ad];
#pragma unroll
            for (int nr = 0; nr < 4; ++nr) {
                acc[mr][nr] = __builtin_amdgcn_mfma_f32_16x16x32_f16(
                    fah, fbh[nr], acc[mr][nr], 0, 0, 0);
                acc[mr][nr] = __builtin_amdgcn_mfma_f32_16x16x32_f16(
                    fah, fbl[nr], acc[mr][nr], 0, 0, 0);
                acc[mr][nr] = __builtin_amdgcn_mfma_f32_16x16x32_f16(
                    fal, fbh[nr], acc[mr][nr], 0, 0, 0);
            }
        }
    }

#pragma unroll
    for (int mr = 0; mr < 4; ++mr)
#pragma unroll
        for (int nr = 0; nr < 4; ++nr) {
            const int col = n0 + wc * 64 + nr * 16 + fr;
#pragma unroll
            for (int q = 0; q < 4; ++q) {
                const int rowc = m0 + wr * 64 + mr * 16 + fg * 4 + q;
                C[(size_t)rowc * N + col] = acc[mr][nr][q];
            }
        }
}

// ---------------------------------------------------------------------------
// Depthwise causal conv (width 4) + bias + SiLU; emits xc as split f16 pair.
// ---------------------------------------------------------------------------
__global__ __launch_bounds__(256) void conv_silu_split_kernel(
    const float* __restrict__ xi, const float* __restrict__ cw,
    const float* __restrict__ cb, _Float16* __restrict__ xch,
    _Float16* __restrict__ xcl)
{
    const int idx = blockIdx.x * 256 + threadIdx.x;   // over MM*DI/4
    const int d4 = idx & (DI / 4 - 1);
    const int bl = idx / (DI / 4);
    const int l  = bl & (LSEQ - 1);
    const int d  = d4 * 4;

    float4 acc = *(const float4*)&cb[d];
    const float4 w0 = *(const float4*)&cw[(d + 0) * 4];
    const float4 w1 = *(const float4*)&cw[(d + 1) * 4];
    const float4 w2 = *(const float4*)&cw[(d + 2) * 4];
    const float4 w3 = *(const float4*)&cw[(d + 3) * 4];

#pragma unroll
    for (int k = 0; k < 4; ++k) {
        const int ll = l - 3 + k;
        if (ll < 0) continue;
        const float4 xv = *(const float4*)&xi[(size_t)(bl - 3 + k) * DI + d];
        const float wk0 = (k == 0) ? w0.x : (k == 1) ? w0.y : (k == 2) ? w0.z : w0.w;
        const float wk1 = (k == 0) ? w1.x : (k == 1) ? w1.y : (k == 2) ? w1.z : w1.w;
        const float wk2 = (k == 0) ? w2.x : (k == 1) ? w2.y : (k == 2) ? w2.z : w2.w;
        const float wk3 = (k == 0) ? w3.x : (k == 1) ? w3.y : (k == 2) ? w3.z : w3.w;
        acc.x = fmaf(xv.x, wk0, acc.x);
        acc.y = fmaf(xv.y, wk1, acc.y);
        acc.z = fmaf(xv.z, wk2, acc.z);
        acc.w = fmaf(xv.w, wk3, acc.w);
    }
    acc.x = acc.x / (1.f + __expf(-acc.x));
    acc.y = acc.y / (1.f + __expf(-acc.y));
    acc.z = acc.z / (1.f + __expf(-acc.z));
    acc.w = acc.w / (1.f + __expf(-acc.w));

    _Float16 h[4], lo4[4];
    h[0] = (_Float16)acc.x; lo4[0] = (_Float16)(acc.x - (float)h[0]);
    h[1] = (_Float16)acc.y; lo4[1] = (_Float16)(acc.y - (float)h[1]);
    h[2] = (_Float16)acc.z; lo4[2] = (_Float16)(acc.z - (float)h[2]);
    h[3] = (_Float16)acc.w; lo4[3] = (_Float16)(acc.w - (float)h[3]);
    *(uint2*)&xch[(size_t)bl * DI + d] = *(uint2*)h;
    *(uint2*)&xcl[(size_t)bl * DI + d] = *(uint2*)lo4;
}

// ---------------------------------------------------------------------------
// xdbl[M][96] = (Xh+Xl)[M][2048] * ((Wh+Wl)[96][2048])^T  via split MFMA.
// 64-row tile, full 96 cols. 4 waves; wave w: rows w*16..w*16+15, 6 n-frags.
// ---------------------------------------------------------------------------
__global__ __launch_bounds__(256) void xdbl_mfma_kernel(
    const _Float16* __restrict__ Xh, const _Float16* __restrict__ Xl,
    const _Float16* __restrict__ Wh, const _Float16* __restrict__ Wl,
    float* __restrict__ xdbl)
{
    __shared__ __align__(16) _Float16 sXh[64 * 32];
    __shared__ __align__(16) _Float16 sXl[64 * 32];
    __shared__ __align__(16) _Float16 sWh[96 * 32];
    __shared__ __align__(16) _Float16 sWl[96 * 32];

    const int t = threadIdx.x;
    const int m0 = blockIdx.x * 64;
    const int l = t & 63, w = t >> 6;
    const int fr = l & 15, fg = l >> 4;

    f32x4 acc[6];
    const f32x4 zz = {0.f, 0.f, 0.f, 0.f};
#pragma unroll
    for (int i = 0; i < 6; ++i) acc[i] = zz;

    // A staging: 64 rows x 4 slots (8 halves) = 256 uint4 -> 1/thread
    const int ar = t >> 2, ac = t & 3;
    const int da = SWIZ(ar, ac);
    const size_t gX = (size_t)(m0 + ar) * DI + ac * 8;
    // B staging: 96 rows x 4 slots = 384 uint4 -> thread t does idx t, t+256(<384)
    const int br0 = t >> 2, bc0 = t & 3;
    const int db0 = SWIZ(br0, bc0);
    const size_t gW0 = (size_t)br0 * DI + bc0 * 8;
    const bool has1 = t < 128;
    const int br1 = (t + 256) >> 2, bc1 = t & 3;
    const int db1 = SWIZ(br1, bc1);
    const size_t gW1 = (size_t)br1 * DI + bc1 * 8;

    uint4 vXh = *(const uint4*)&Xh[gX], vXl = *(const uint4*)&Xl[gX];
    uint4 vWh0 = *(const uint4*)&Wh[gW0], vWl0 = *(const uint4*)&Wl[gW0];
    uint4 vWh1, vWl1;
    if (has1) { vWh1 = *(const uint4*)&Wh[gW1]; vWl1 = *(const uint4*)&Wl[gW1]; }

    const int nk = DI / 32;
    for (int kt = 0; kt < nk; ++kt) {
        __syncthreads();
        *(uint4*)&sXh[da] = vXh;   *(uint4*)&sXl[da] = vXl;
        *(uint4*)&sWh[db0] = vWh0; *(uint4*)&sWl[db0] = vWl0;
        if (has1) { *(uint4*)&sWh[db1] = vWh1; *(uint4*)&sWl[db1] = vWl1; }
        __syncthreads();

        if (kt + 1 < nk) {
            const size_t o = (size_t)(kt + 1) * 32;
            vXh = *(const uint4*)&Xh[gX + o];   vXl = *(const uint4*)&Xl[gX + o];
            vWh0 = *(const uint4*)&Wh[gW0 + o]; vWl0 = *(const uint4*)&Wl[gW0 + o];
            if (has1) { vWh1 = *(const uint4*)&Wh[gW1 + o]; vWl1 = *(const uint4*)&Wl[gW1 + o]; }
        }

        const int aad = SWIZ(w * 16 + fr, fg);
        const f16x8 fah = *(const f16x8*)&sXh[aad];
        const f16x8 fal = *(const f16x8*)&sXl[aad];
#pragma unroll
        for (int nr = 0; nr < 6; ++nr) {
            const int bad = SWIZ(nr * 16 + fr, fg);
            const f16x8 fbh = *(const f16x8*)&sWh[bad];
            const f16x8 fbl = *(const f16x8*)&sWl[bad];
            acc[nr] = __builtin_amdgcn_mfma_f32_16x16x32_f16(fah, fbh, acc[nr], 0, 0, 0);
            acc[nr] = __builtin_amdgcn_mfma_f32_16x16x32_f16(fah, fbl, acc[nr], 0, 0, 0);
            acc[nr] = __builtin_amdgcn_mfma_f32_16x16x32_f16(fal, fbh, acc[nr], 0, 0, 0);
        }
    }

#pragma unroll
    for (int nr = 0; nr < 6; ++nr) {
        const int col = nr * 16 + fr;
#pragma unroll
        for (int q = 0; q < 4; ++q) {
            const int row = m0 + w * 16 + fg * 4 + q;
            xdbl[(size_t)row * 96 + col] = acc[nr][q];
        }
    }
}

// ---------------------------------------------------------------------------
// dt[M][DI] = softplus(dt_lo[M][64] * W_dt[DI][64]^T + b_dt)   (unchanged)
// ---------------------------------------------------------------------------
__global__ __launch_bounds__(256) void dt_kernel(
    const float* __restrict__ xdbl, const float* __restrict__ Wdt,
    const float* __restrict__ bdt, float* __restrict__ dt)
{
    __shared__ float s[16][64];
    const int t = threadIdx.x;
    const int m0 = blockIdx.y * 16;

    {
        const int row = t >> 4, c4 = t & 15;
        *(float4*)&s[row][c4 * 4] =
            *(const float4*)&xdbl[(size_t)(m0 + row) * 96 + c4 * 4];
    }
    __syncthreads();

    const int n = blockIdx.x * 256 + t;
    float4 w[16];
#pragma unroll
    for (int k4 = 0; k4 < 16; ++k4)
        w[k4] = *(const float4*)&Wdt[(size_t)n * 64 + k4 * 4];
    const float bd = bdt[n];

#pragma unroll
    for (int i = 0; i < 16; ++i) {
        float acc = bd;
#pragma unroll
        for (int k4 = 0; k4 < 16; ++k4) {
            acc += s[i][k4*4+0] * w[k4].x + s[i][k4*4+1] * w[k4].y
                 + s[i][k4*4+2] * w[k4].z + s[i][k4*4+3] * w[k4].w;
        }
        const float sp = (acc > 20.f) ? acc : log1pf(__expf(acc));
        dt[(size_t)(m0 + i) * DI + n] = sp;
    }
}

// ---------------------------------------------------------------------------
// Selective scan, phase-batched; xc arrives as split f16 pair (hi+lo).
// ---------------------------------------------------------------------------
__global__ __launch_bounds__(256) void scan_kernel(
    const float* __restrict__ dt,
    const _Float16* __restrict__ xch, const _Float16* __restrict__ xcl,
    const float* __restrict__ xdbl, const float* z,
    const float* __restrict__ A_log, const float* __restrict__ D_skip,
    float* y)
{
    __shared__ float s_dt[CHUNK][16];
    __shared__ float s_xc[CHUNK][16];
    __shared__ float s_z [CHUNK][16];   // z in, y out
    __shared__ float s_B [CHUNK][16];
    __shared__ float s_C [CHUNK][16];
    __shared__ float s_p [16][16][17];  // [g][j][s] pad 17
    __shared__ float s_D [16];

    const int t = threadIdx.x;
    const int g = t >> 4;
    const int s = t & 15;
    const int c = blockIdx.x * 16 + g;
    const int b = c >> 11;
    const int d = c & (DI - 1);
    const int d0 = (blockIdx.x * 16) & (DI - 1);

    const int lr = t >> 2;
    const int lc = t & 3;

    if (t < 16) s_D[t] = D_skip[d0 + t];

    const float Acoef = -__expf(A_log[d * DSTATE + s]);
    const size_t rbase = (size_t)b * LSEQ;

    float h = 0.f;
    float4 r_dt, r_z, r_B, r_C;
    f16x4 r_xh, r_xl;

    {
        const size_t row = rbase + lr;
        r_dt = *(const float4*)&dt[row * DI + d0 + lc * 4];
        r_xh = *(const f16x4*)&xch[row * DI + d0 + lc * 4];
        r_xl = *(const f16x4*)&xcl[row * DI + d0 + lc * 4];
        r_z  = *(const float4*)&z [row * DI + d0 + lc * 4];
        r_B  = *(const float4*)&xdbl[row * 96 + DRANK + lc * 4];
        r_C  = *(const float4*)&xdbl[row * 96 + DRANK + DSTATE + lc * 4];
    }

    for (int ch = 0; ch < LSEQ / CHUNK; ++ch) {
        __syncthreads();
        *(float4*)&s_dt[lr][lc * 4] = r_dt;
        {
            float4 xf;
            xf.x = (float)r_xh[0] + (float)r_xl[0];
            xf.y = (float)r_xh[1] + (float)r_xl[1];
            xf.z = (float)r_xh[2] + (float)r_xl[2];
            xf.w = (float)r_xh[3] + (float)r_xl[3];
            *(float4*)&s_xc[lr][lc * 4] = xf;
        }
        *(float4*)&s_z [lr][lc * 4] = r_z;
        *(float4*)&s_B [lr][lc * 4] = r_B;
        *(float4*)&s_C [lr][lc * 4] = r_C;
        __syncthreads();

        if (ch + 1 < LSEQ / CHUNK) {
            const size_t row = rbase + (size_t)(ch + 1) * CHUNK + lr;
            r_dt = *(const float4*)&dt[row * DI + d0 + lc * 4];
            r_xh = *(const f16x4*)&xch[row * DI + d0 + lc * 4];
            r_xl = *(const f16x4*)&xcl[row * DI + d0 + lc * 4];
            r_z  = *(const float4*)&z [row * DI + d0 + lc * 4];
            r_B  = *(const float4*)&xdbl[row * 96 + DRANK + lc * 4];
            r_C  = *(const float4*)&xdbl[row * 96 + DRANK + DSTATE + lc * 4];
        }

#pragma unroll
        for (int sub = 0; sub < CHUNK / 16; ++sub) {
            const int base = sub * 16;
            float dA[16], u[16], Cv[16];
#pragma unroll
            for (int j = 0; j < 16; ++j) {
                const float dtv = s_dt[base + j][g];
                const float xv  = s_xc[base + j][g];
                const float Bv  = s_B [base + j][s];
                Cv[j] = s_C[base + j][s];
                dA[j] = __expf(dtv * Acoef);
                u[j]  = dtv * xv * Bv;
            }
#pragma unroll
            for (int j = 0; j < 16; ++j) {
                h = fmaf(dA[j], h, u[j]);
                s_p[g][j][s] = h * Cv[j];
            }
            __syncthreads();
            float accp = 0.f;
#pragma unroll
            for (int k = 0; k < 16; ++k)
                accp += s_p[g][s][k];
            {
                const int row = base + s;
                const float xv = s_xc[row][g];
                const float zv = s_z [row][g];
                const float sig = 1.f / (1.f + __expf(-zv));
                s_z[row][g] = fmaf(xv, s_D[g], accp) * (zv * sig);
            }
            __syncthreads();
        }
        {
            const size_t row = rbase + (size_t)ch * CHUNK + lr;
            *(float4*)&y[row * DI + d0 + lc * 4] = *(const float4*)&s_z[lr][lc * 4];
        }
    }
}

// ---------------------------------------------------------------------------
extern "C" void kernel_launch(void* const* d_in, const int* in_sizes, int n_in,
                              void* d_out, int out_size, void* d_ws, size_t ws_size,
                              hipStream_t stream)
{
    const float* x      = (const float*)d_in[0];
    const float* W_in   = (const float*)d_in[1];
    const float* cw     = (const float*)d_in[2];
    const float* cb     = (const float*)d_in[3];
    const float* W_x    = (const float*)d_in[4];
    const float* W_dt   = (const float*)d_in[5];
    const float* b_dt   = (const float*)d_in[6];
    const float* A_log  = (const float*)d_in[7];
    const float* D_skip = (const float*)d_in[8];
    const float* W_out  = (const float*)d_in[9];
    float* out = (float*)d_out;

    // fp32 workspace (identical 205MB footprint to rounds 2-5):
    const size_t MMDI = (size_t)MM * DI;
    float* xi  = (float*)d_ws;          // xz-half -> Wx-split -> dt -> Wout-split
    float* zb  = xi  + MMDI;            // z -> y (in-place)
    float* xcb = zb  + MMDI;            // x/Win splits -> xc split pair -> y splits
    float* xdb = xcb + MMDI;            // MM*96

    // f16 aliases (all inside dead fp32 regions at their time of use)
    _Float16* xh   = (_Float16*)xcb;                 // MM*DM
    _Float16* xl   = xh + (size_t)MM * DM;
    _Float16* Winh = xl + (size_t)MM * DM;           // 2*DI*DM
    _Float16* Winl = Winh + (size_t)2 * DI * DM;
    _Float16* xch  = (_Float16*)xcb;                 // MM*DI (after GEMM1, conv out)
    _Float16* xcl  = xch + MMDI;
    _Float16* Wxh  = (_Float16*)xi;                  // 96*DI (post-conv dead window)
    _Float16* Wxl  = Wxh + (size_t)96 * DI;
    _Float16* yh   = (_Float16*)xcb;                 // MM*DI (after scan)
    _Float16* yl   = yh + MMDI;
    _Float16* Woh  = (_Float16*)xi;                  // DM*DI (after scan)
    _Float16* Wol  = Woh + (size_t)DM * DI;

    const dim3 blk(256);

    // split inputs of GEMM1
    split_kernel<<<dim3((MM * DM / 4) / 256), blk, 0, stream>>>(x, xh, xl, MM * DM / 4);
    split_kernel<<<dim3((2 * DI * DM / 4) / 256), blk, 0, stream>>>(
        W_in, Winh, Winl, 2 * DI * DM / 4);

    // xz = x @ W_in^T, xi / z halves (MFMA split GEMM)
    gemm_nt_split<<<dim3(DI / 128, MM / 128), blk, 0, stream>>>(
        xi, xh, xl, Winh, Winl, MM, DI, DM);
    gemm_nt_split<<<dim3(DI / 128, MM / 128), blk, 0, stream>>>(
        zb, xh, xl, Winh + (size_t)DI * DM, Winl + (size_t)DI * DM, MM, DI, DM);

    // conv overwrites xcb with split-f16 xc (x/Win splits dead now)
    conv_silu_split_kernel<<<dim3(MM * (DI / 4) / 256), blk, 0, stream>>>(
        xi, cw, cb, xch, xcl);

    // W_x split into xi slab (dead between conv and dt_kernel)
    split_kernel<<<dim3((96 * DI / 4) / 256), blk, 0, stream>>>(
        W_x, Wxh, Wxl, 96 * DI / 4);

    xdbl_mfma_kernel<<<dim3(MM / 64), blk, 0, stream>>>(xch, xcl, Wxh, Wxl, xdb);

    dt_kernel<<<dim3(DI / 256, MM / 16), blk, 0, stream>>>(xdb, W_dt, b_dt, xi);

    scan_kernel<<<dim3(BB * DI / 16), blk, 0, stream>>>(
        xi, xch, xcl, xdb, zb, A_log, D_skip, zb);

    // split GEMM4 inputs into now-dead regions
    split_kernel<<<dim3((MM * DI / 4) / 256), blk, 0, stream>>>(zb, yh, yl, MM * DI / 4);
    split_kernel<<<dim3((DM * DI / 4) / 256), blk, 0, stream>>>(
        W_out, Woh, Wol, DM * DI / 4);

    gemm_nt_split<<<dim3(DM / 128, MM / 128), blk, 0, stream>>>(
        out, yh, yl, Woh, Wol, MM, DM, DI);
}

// Round 7
// 788.933 us; speedup vs baseline: 2.7703x; 1.0486x over previous
//
#include <hip/hip_runtime.h>
#include <hip/hip_bf16.h>

// Problem constants (match reference)
#define DM    1024   // D_MODEL
#define DI    2048   // D_INNER
#define DCONV 4
#define DSTATE 16
#define DRANK 64
#define BB    4
#define LSEQ  2048
#define MM    (BB*LSEQ)   // 8192 rows
#define CHUNK 64          // scan LDS-staging chunk (timesteps)

typedef _Float16 f16x8 __attribute__((ext_vector_type(8)));
typedef _Float16 f16x4 __attribute__((ext_vector_type(4)));
typedef float    f32x4 __attribute__((ext_vector_type(4)));

// LDS swizzle: 16B slot within a 64B row, XOR'd so 16-row column reads are
// 2-way (free). global_load_lds writes linearly, so the write side achieves
// the same permutation via pre-swizzled per-lane GLOBAL source addresses
// (linear dest + inverse-swz source + swz read; XOR is its own inverse).
#define SWIZMASK(row) (((row) & 3) ^ (((row) >> 2) & 1))
#define SWIZ(row, g)  ((((row) * 4) + ((g) ^ SWIZMASK(row))) * 8)

#define GLOAD_LDS16(gp, sp) __builtin_amdgcn_global_load_lds( \
    (const __attribute__((address_space(1))) void*)(gp),      \
    (__attribute__((address_space(3))) void*)(sp), 16, 0, 0)

// ---------------------------------------------------------------------------
// split: fp32 -> (hi, lo) f16 pair.  lo = f16(x - float(hi)); x==hi+lo+O(2^-22)
// ---------------------------------------------------------------------------
__global__ __launch_bounds__(256) void split_kernel(
    const float* __restrict__ in, _Float16* __restrict__ hi,
    _Float16* __restrict__ lo, int n4)
{
    const int i = blockIdx.x * 256 + threadIdx.x;
    if (i >= n4) return;
    const float4 v = ((const float4*)in)[i];
    _Float16 h[4], l[4];
    h[0] = (_Float16)v.x; l[0] = (_Float16)(v.x - (float)h[0]);
    h[1] = (_Float16)v.y; l[1] = (_Float16)(v.y - (float)h[1]);
    h[2] = (_Float16)v.z; l[2] = (_Float16)(v.z - (float)h[2]);
    h[3] = (_Float16)v.w; l[3] = (_Float16)(v.w - (float)h[3]);
    *(uint2*)&hi[(size_t)i * 4] = *(uint2*)h;
    *(uint2*)&lo[(size_t)i * 4] = *(uint2*)l;
}

// ---------------------------------------------------------------------------
// Split-precision MFMA GEMM NT, global_load_lds staging (m97 structure).
// C[M][N] = (Ah+Al)[M][K] * ((Bh+Bl)[N][K])^T, 3 MFMA products.
// 128x128 tile, BK=32, 4 waves; per K-step each wave issues 8
// global_load_lds (2 chunks x 4 arrays); source col pre-swizzled.
// ---------------------------------------------------------------------------
__global__ __launch_bounds__(256) void gemm_nt_split(
    float* __restrict__ C,
    const _Float16* __restrict__ Ah, const _Float16* __restrict__ Al,
    const _Float16* __restrict__ Bh, const _Float16* __restrict__ Bl,
    int M, int N, int K)
{
    __shared__ __align__(16) _Float16 sAh[128 * 32];
    __shared__ __align__(16) _Float16 sAl[128 * 32];
    __shared__ __align__(16) _Float16 sBh[128 * 32];
    __shared__ __align__(16) _Float16 sBl[128 * 32];

    const int t = threadIdx.x;
    const int m0 = blockIdx.y * 128, n0 = blockIdx.x * 128;
    const int l = t & 63, w = t >> 6;
    const int wr = w >> 1, wc = w & 1;
    const int fr = l & 15, fg = l >> 4;

    f32x4 acc[4][4];
    const f32x4 zz = {0.f, 0.f, 0.f, 0.f};
#pragma unroll
    for (int i = 0; i < 4; ++i)
#pragma unroll
        for (int j = 0; j < 4; ++j) acc[i][j] = zz;

    // wave w stages chunks {2w, 2w+1}: chunk ch = rows ch*16..+15, 1KB.
    // lane l -> slot ch*64+l -> row ch*16+(l>>2), slot-pos l&3;
    // fetch global 16B group (l&3) ^ SWIZMASK(row).
    const int ch0 = w * 2, ch1 = w * 2 + 1;
    const int g4 = l & 3;
    const int rA0 = ch0 * 16 + (l >> 2), rA1 = ch1 * 16 + (l >> 2);
    const int c0 = (g4 ^ SWIZMASK(rA0)) * 8, c1 = (g4 ^ SWIZMASK(rA1)) * 8;
    const size_t gA0 = (size_t)(m0 + rA0) * K + c0;
    const size_t gA1 = (size_t)(m0 + rA1) * K + c1;
    const size_t gB0 = (size_t)(n0 + rA0) * K + c0;
    const size_t gB1 = (size_t)(n0 + rA1) * K + c1;
    const int lo0 = ch0 * 512, lo1 = ch1 * 512;   // halves: chunk LDS base

    const int nk = K / 32;
    for (int kt = 0; kt < nk; ++kt) {
        const size_t ko = (size_t)kt * 32;
        GLOAD_LDS16(&Ah[gA0 + ko], &sAh[lo0]);
        GLOAD_LDS16(&Ah[gA1 + ko], &sAh[lo1]);
        GLOAD_LDS16(&Al[gA0 + ko], &sAl[lo0]);
        GLOAD_LDS16(&Al[gA1 + ko], &sAl[lo1]);
        GLOAD_LDS16(&Bh[gB0 + ko], &sBh[lo0]);
        GLOAD_LDS16(&Bh[gB1 + ko], &sBh[lo1]);
        GLOAD_LDS16(&Bl[gB0 + ko], &sBl[lo0]);
        GLOAD_LDS16(&Bl[gB1 + ko], &sBl[lo1]);
        __syncthreads();   // compiler drains vmcnt(0) before s_barrier

        f16x8 fbh[4], fbl[4];
#pragma unroll
        for (int nr = 0; nr < 4; ++nr) {
            const int row = wc * 64 + nr * 16 + fr;
            const int ad = SWIZ(row, fg);
            fbh[nr] = *(const f16x8*)&sBh[ad];
            fbl[nr] = *(const f16x8*)&sBl[ad];
        }
#pragma unroll
        for (int mr = 0; mr < 4; ++mr) {
            const int row = wr * 64 + mr * 16 + fr;
            const int ad = SWIZ(row, fg);
            const f16x8 fah = *(const f16x8*)&sAh[ad];
            const f16x8 fal = *(const f16x8*)&sAl[ad];
#pragma unroll
            for (int nr = 0; nr < 4; ++nr) {
                acc[mr][nr] = __builtin_amdgcn_mfma_f32_16x16x32_f16(
                    fah, fbh[nr], acc[mr][nr], 0, 0, 0);
                acc[mr][nr] = __builtin_amdgcn_mfma_f32_16x16x32_f16(
                    fah, fbl[nr], acc[mr][nr], 0, 0, 0);
                acc[mr][nr] = __builtin_amdgcn_mfma_f32_16x16x32_f16(
                    fal, fbh[nr], acc[mr][nr], 0, 0, 0);
            }
        }
        __syncthreads();   // LDS consumed before next tile's writes
    }

#pragma unroll
    for (int mr = 0; mr < 4; ++mr)
#pragma unroll
        for (int nr = 0; nr < 4; ++nr) {
            const int col = n0 + wc * 64 + nr * 16 + fr;
#pragma unroll
            for (int q = 0; q < 4; ++q) {
                const int rowc = m0 + wr * 64 + mr * 16 + fg * 4 + q;
                C[(size_t)rowc * N + col] = acc[mr][nr][q];
            }
        }
}

// ---------------------------------------------------------------------------
// dt[M][2048] = softplus(xdbl[:, :64] * W_dt[2048][64]^T + b_dt)
// Split-MFMA with in-flight fp32->f16 split during LDS staging. BK=32, nk=2.
// ---------------------------------------------------------------------------
__global__ __launch_bounds__(256) void dt_mfma_kernel(
    const float* __restrict__ xdbl, const float* __restrict__ Wdt,
    const float* __restrict__ bdt, float* __restrict__ dtout)
{
    __shared__ __align__(16) _Float16 sAh[128 * 32];
    __shared__ __align__(16) _Float16 sAl[128 * 32];
    __shared__ __align__(16) _Float16 sBh[128 * 32];
    __shared__ __align__(16) _Float16 sBl[128 * 32];

    const int t = threadIdx.x;
    const int m0 = blockIdx.y * 128, n0 = blockIdx.x * 128;
    const int l = t & 63, w = t >> 6;
    const int wr = w >> 1, wc = w & 1;
    const int fr = l & 15, fg = l >> 4;

    f32x4 acc[4][4];
    const f32x4 zz = {0.f, 0.f, 0.f, 0.f};
#pragma unroll
    for (int i = 0; i < 4; ++i)
#pragma unroll
        for (int j = 0; j < 4; ++j) acc[i][j] = zz;

#pragma unroll
    for (int kt = 0; kt < 2; ++kt) {
        __syncthreads();
#pragma unroll
        for (int ss = 0; ss < 2; ++ss) {
            const int s = t + ss * 256;
            const int row = s >> 2, c = s & 3;
            const int dst = SWIZ(row, c);
            {   // A from xdbl cols [kt*32 + c*8 .. +7]  (row stride 96)
                const float* p = &xdbl[(size_t)(m0 + row) * 96 + kt * 32 + c * 8];
                const float4 a0 = *(const float4*)p, a1 = *(const float4*)(p + 4);
                _Float16 h[8], lo8[8];
                const float vv[8] = {a0.x,a0.y,a0.z,a0.w,a1.x,a1.y,a1.z,a1.w};
#pragma unroll
                for (int q = 0; q < 8; ++q) {
                    h[q] = (_Float16)vv[q]; lo8[q] = (_Float16)(vv[q] - (float)h[q]);
                }
                *(uint4*)&sAh[dst] = *(uint4*)h;
                *(uint4*)&sAl[dst] = *(uint4*)lo8;
            }
            {   // B from W_dt (row stride 64)
                const float* p = &Wdt[(size_t)(n0 + row) * 64 + kt * 32 + c * 8];
                const float4 b0 = *(const float4*)p, b1 = *(const float4*)(p + 4);
                _Float16 h[8], lo8[8];
                const float vv[8] = {b0.x,b0.y,b0.z,b0.w,b1.x,b1.y,b1.z,b1.w};
#pragma unroll
                for (int q = 0; q < 8; ++q) {
                    h[q] = (_Float16)vv[q]; lo8[q] = (_Float16)(vv[q] - (float)h[q]);
                }
                *(uint4*)&sBh[dst] = *(uint4*)h;
                *(uint4*)&sBl[dst] = *(uint4*)lo8;
            }
        }
        __syncthreads();

        f16x8 fbh[4], fbl[4];
#pragma unroll
        for (int nr = 0; nr < 4; ++nr) {
            const int row = wc * 64 + nr * 16 + fr;
            const int ad = SWIZ(row, fg);
            fbh[nr] = *(const f16x8*)&sBh[ad];
            fbl[nr] = *(const f16x8*)&sBl[ad];
        }
#pragma unroll
        for (int mr = 0; mr < 4; ++mr) {
            const int row = wr * 64 + mr * 16 + fr;
            const int ad = SWIZ(row, fg);
            const f16x8 fah = *(const f16x8*)&sAh[ad];
            const f16x8 fal = *(const f16x8*)&sAl[ad];
#pragma unroll
            for (int nr = 0; nr < 4; ++nr) {
                acc[mr][nr] = __builtin_amdgcn_mfma_f32_16x16x32_f16(
                    fah, fbh[nr], acc[mr][nr], 0, 0, 0);
                acc[mr][nr] = __builtin_amdgcn_mfma_f32_16x16x32_f16(
                    fah, fbl[nr], acc[mr][nr], 0, 0, 0);
                acc[mr][nr] = __builtin_amdgcn_mfma_f32_16x16x32_f16(
                    fal, fbh[nr], acc[mr][nr], 0, 0, 0);
            }
        }
    }

#pragma unroll
    for (int mr = 0; mr < 4; ++mr)
#pragma unroll
        for (int nr = 0; nr < 4; ++nr) {
            const int col = n0 + wc * 64 + nr * 16 + fr;
            const float bd = bdt[col];
#pragma unroll
            for (int q = 0; q < 4; ++q) {
                const int rowc = m0 + wr * 64 + mr * 16 + fg * 4 + q;
                const float v = acc[mr][nr][q] + bd;
                dtout[(size_t)rowc * DI + col] =
                    (v > 20.f) ? v : log1pf(__expf(v));
            }
        }
}

// ---------------------------------------------------------------------------
// Depthwise causal conv (width 4) + bias + SiLU; emits xc as split f16 pair.
// ---------------------------------------------------------------------------
__global__ __launch_bounds__(256) void conv_silu_split_kernel(
    const float* __restrict__ xi, const float* __restrict__ cw,
    const float* __restrict__ cb, _Float16* __restrict__ xch,
    _Float16* __restrict__ xcl)
{
    const int idx = blockIdx.x * 256 + threadIdx.x;   // over MM*DI/4
    const int d4 = idx & (DI / 4 - 1);
    const int bl = idx / (DI / 4);
    const int l  = bl & (LSEQ - 1);
    const int d  = d4 * 4;

    float4 acc = *(const float4*)&cb[d];
    const float4 w0 = *(const float4*)&cw[(d + 0) * 4];
    const float4 w1 = *(const float4*)&cw[(d + 1) * 4];
    const float4 w2 = *(const float4*)&cw[(d + 2) * 4];
    const float4 w3 = *(const float4*)&cw[(d + 3) * 4];

#pragma unroll
    for (int k = 0; k < 4; ++k) {
        const int ll = l - 3 + k;
        if (ll < 0) continue;
        const float4 xv = *(const float4*)&xi[(size_t)(bl - 3 + k) * DI + d];
        const float wk0 = (k == 0) ? w0.x : (k == 1) ? w0.y : (k == 2) ? w0.z : w0.w;
        const float wk1 = (k == 0) ? w1.x : (k == 1) ? w1.y : (k == 2) ? w1.z : w1.w;
        const float wk2 = (k == 0) ? w2.x : (k == 1) ? w2.y : (k == 2) ? w2.z : w2.w;
        const float wk3 = (k == 0) ? w3.x : (k == 1) ? w3.y : (k == 2) ? w3.z : w3.w;
        acc.x = fmaf(xv.x, wk0, acc.x);
        acc.y = fmaf(xv.y, wk1, acc.y);
        acc.z = fmaf(xv.z, wk2, acc.z);
        acc.w = fmaf(xv.w, wk3, acc.w);
    }
    acc.x = acc.x / (1.f + __expf(-acc.x));
    acc.y = acc.y / (1.f + __expf(-acc.y));
    acc.z = acc.z / (1.f + __expf(-acc.z));
    acc.w = acc.w / (1.f + __expf(-acc.w));

    _Float16 h[4], lo4[4];
    h[0] = (_Float16)acc.x; lo4[0] = (_Float16)(acc.x - (float)h[0]);
    h[1] = (_Float16)acc.y; lo4[1] = (_Float16)(acc.y - (float)h[1]);
    h[2] = (_Float16)acc.z; lo4[2] = (_Float16)(acc.z - (float)h[2]);
    h[3] = (_Float16)acc.w; lo4[3] = (_Float16)(acc.w - (float)h[3]);
    *(uint2*)&xch[(size_t)bl * DI + d] = *(uint2*)h;
    *(uint2*)&xcl[(size_t)bl * DI + d] = *(uint2*)lo4;
}

// ---------------------------------------------------------------------------
// xdbl[M][96] = (Xh+Xl)[M][2048] * ((Wh+Wl)[96][2048])^T  (unchanged)
// ---------------------------------------------------------------------------
__global__ __launch_bounds__(256) void xdbl_mfma_kernel(
    const _Float16* __restrict__ Xh, const _Float16* __restrict__ Xl,
    const _Float16* __restrict__ Wh, const _Float16* __restrict__ Wl,
    float* __restrict__ xdbl)
{
    __shared__ __align__(16) _Float16 sXh[64 * 32];
    __shared__ __align__(16) _Float16 sXl[64 * 32];
    __shared__ __align__(16) _Float16 sWh[96 * 32];
    __shared__ __align__(16) _Float16 sWl[96 * 32];

    const int t = threadIdx.x;
    const int m0 = blockIdx.x * 64;
    const int l = t & 63, w = t >> 6;
    const int fr = l & 15, fg = l >> 4;

    f32x4 acc[6];
    const f32x4 zz = {0.f, 0.f, 0.f, 0.f};
#pragma unroll
    for (int i = 0; i < 6; ++i) acc[i] = zz;

    const int ar = t >> 2, ac = t & 3;
    const int da = SWIZ(ar, ac);
    const size_t gX = (size_t)(m0 + ar) * DI + ac * 8;
    const int br0 = t >> 2, bc0 = t & 3;
    const int db0 = SWIZ(br0, bc0);
    const size_t gW0 = (size_t)br0 * DI + bc0 * 8;
    const bool has1 = t < 128;
    const int br1 = (t + 256) >> 2, bc1 = t & 3;
    const int db1 = SWIZ(br1, bc1);
    const size_t gW1 = (size_t)br1 * DI + bc1 * 8;

    uint4 vXh = *(const uint4*)&Xh[gX], vXl = *(const uint4*)&Xl[gX];
    uint4 vWh0 = *(const uint4*)&Wh[gW0], vWl0 = *(const uint4*)&Wl[gW0];
    uint4 vWh1, vWl1;
    if (has1) { vWh1 = *(const uint4*)&Wh[gW1]; vWl1 = *(const uint4*)&Wl[gW1]; }

    const int nk = DI / 32;
    for (int kt = 0; kt < nk; ++kt) {
        __syncthreads();
        *(uint4*)&sXh[da] = vXh;   *(uint4*)&sXl[da] = vXl;
        *(uint4*)&sWh[db0] = vWh0; *(uint4*)&sWl[db0] = vWl0;
        if (has1) { *(uint4*)&sWh[db1] = vWh1; *(uint4*)&sWl[db1] = vWl1; }
        __syncthreads();

        if (kt + 1 < nk) {
            const size_t o = (size_t)(kt + 1) * 32;
            vXh = *(const uint4*)&Xh[gX + o];   vXl = *(const uint4*)&Xl[gX + o];
            vWh0 = *(const uint4*)&Wh[gW0 + o]; vWl0 = *(const uint4*)&Wl[gW0 + o];
            if (has1) { vWh1 = *(const uint4*)&Wh[gW1 + o]; vWl1 = *(const uint4*)&Wl[gW1 + o]; }
        }

        const int aad = SWIZ(w * 16 + fr, fg);
        const f16x8 fah = *(const f16x8*)&sXh[aad];
        const f16x8 fal = *(const f16x8*)&sXl[aad];
#pragma unroll
        for (int nr = 0; nr < 6; ++nr) {
            const int bad = SWIZ(nr * 16 + fr, fg);
            const f16x8 fbh = *(const f16x8*)&sWh[bad];
            const f16x8 fbl = *(const f16x8*)&sWl[bad];
            acc[nr] = __builtin_amdgcn_mfma_f32_16x16x32_f16(fah, fbh, acc[nr], 0, 0, 0);
            acc[nr] = __builtin_amdgcn_mfma_f32_16x16x32_f16(fah, fbl, acc[nr], 0, 0, 0);
            acc[nr] = __builtin_amdgcn_mfma_f32_16x16x32_f16(fal, fbh, acc[nr], 0, 0, 0);
        }
    }

#pragma unroll
    for (int nr = 0; nr < 6; ++nr) {
        const int col = nr * 16 + fr;
#pragma unroll
        for (int q = 0; q < 4; ++q) {
            const int row = m0 + w * 16 + fg * 4 + q;
            xdbl[(size_t)row * 96 + col] = acc[nr][q];
        }
    }
}

// ---------------------------------------------------------------------------
// Selective scan, phase-batched. s_xc/s_z padded to stride 20 (80B, float4-
// aligned) so reduce-phase [row][g] accesses are 2-way instead of 8-way.
// ---------------------------------------------------------------------------
__global__ __launch_bounds__(256) void scan_kernel(
    const float* __restrict__ dt,
    const _Float16* __restrict__ xch, const _Float16* __restrict__ xcl,
    const float* __restrict__ xdbl, const float* z,
    const float* __restrict__ A_log, const float* __restrict__ D_skip,
    float* y)
{
    __shared__ float s_dt[CHUNK][16];
    __shared__ float s_xc[CHUNK][20];   // padded
    __shared__ float s_z [CHUNK][20];   // padded; z in, y out
    __shared__ float s_B [CHUNK][16];
    __shared__ float s_C [CHUNK][16];
    __shared__ float s_p [16][16][17];
    __shared__ float s_D [16];

    const int t = threadIdx.x;
    const int g = t >> 4;
    const int s = t & 15;
    const int c = blockIdx.x * 16 + g;
    const int b = c >> 11;
    const int d = c & (DI - 1);
    const int d0 = (blockIdx.x * 16) & (DI - 1);

    const int lr = t >> 2;
    const int lc = t & 3;

    if (t < 16) s_D[t] = D_skip[d0 + t];

    const float Acoef = -__expf(A_log[d * DSTATE + s]);
    const size_t rbase = (size_t)b * LSEQ;

    float h = 0.f;
    float4 r_dt, r_z, r_B, r_C;
    f16x4 r_xh, r_xl;

    {
        const size_t row = rbase + lr;
        r_dt = *(const float4*)&dt[row * DI + d0 + lc * 4];
        r_xh = *(const f16x4*)&xch[row * DI + d0 + lc * 4];
        r_xl = *(const f16x4*)&xcl[row * DI + d0 + lc * 4];
        r_z  = *(const float4*)&z [row * DI + d0 + lc * 4];
        r_B  = *(const float4*)&xdbl[row * 96 + DRANK + lc * 4];
        r_C  = *(const float4*)&xdbl[row * 96 + DRANK + DSTATE + lc * 4];
    }

    for (int ch = 0; ch < LSEQ / CHUNK; ++ch) {
        __syncthreads();
        *(float4*)&s_dt[lr][lc * 4] = r_dt;
        {
            float4 xf;
            xf.x = (float)r_xh[0] + (float)r_xl[0];
            xf.y = (float)r_xh[1] + (float)r_xl[1];
            xf.z = (float)r_xh[2] + (float)r_xl[2];
            xf.w = (float)r_xh[3] + (float)r_xl[3];
            *(float4*)&s_xc[lr][lc * 4] = xf;
        }
        *(float4*)&s_z [lr][lc * 4] = r_z;
        *(float4*)&s_B [lr][lc * 4] = r_B;
        *(float4*)&s_C [lr][lc * 4] = r_C;
        __syncthreads();

        if (ch + 1 < LSEQ / CHUNK) {
            const size_t row = rbase + (size_t)(ch + 1) * CHUNK + lr;
            r_dt = *(const float4*)&dt[row * DI + d0 + lc * 4];
            r_xh = *(const f16x4*)&xch[row * DI + d0 + lc * 4];
            r_xl = *(const f16x4*)&xcl[row * DI + d0 + lc * 4];
            r_z  = *(const float4*)&z [row * DI + d0 + lc * 4];
            r_B  = *(const float4*)&xdbl[row * 96 + DRANK + lc * 4];
            r_C  = *(const float4*)&xdbl[row * 96 + DRANK + DSTATE + lc * 4];
        }

#pragma unroll
        for (int sub = 0; sub < CHUNK / 16; ++sub) {
            const int base = sub * 16;
            float dA[16], u[16], Cv[16];
#pragma unroll
            for (int j = 0; j < 16; ++j) {
                const float dtv = s_dt[base + j][g];
                const float xv  = s_xc[base + j][g];
                const float Bv  = s_B [base + j][s];
                Cv[j] = s_C[base + j][s];
                dA[j] = __expf(dtv * Acoef);
                u[j]  = dtv * xv * Bv;
            }
#pragma unroll
            for (int j = 0; j < 16; ++j) {
                h = fmaf(dA[j], h, u[j]);
                s_p[g][j][s] = h * Cv[j];
            }
            __syncthreads();
            float accp = 0.f;
#pragma unroll
            for (int k = 0; k < 16; ++k)
                accp += s_p[g][s][k];
            {
                const int row = base + s;
                const float xv = s_xc[row][g];
                const float zv = s_z [row][g];
                const float sig = 1.f / (1.f + __expf(-zv));
                s_z[row][g] = fmaf(xv, s_D[g], accp) * (zv * sig);
            }
            __syncthreads();
        }
        {
            const size_t row = rbase + (size_t)ch * CHUNK + lr;
            *(float4*)&y[row * DI + d0 + lc * 4] = *(const float4*)&s_z[lr][lc * 4];
        }
    }
}

// ---------------------------------------------------------------------------
extern "C" void kernel_launch(void* const* d_in, const int* in_sizes, int n_in,
                              void* d_out, int out_size, void* d_ws, size_t ws_size,
                              hipStream_t stream)
{
    const float* x      = (const float*)d_in[0];
    const float* W_in   = (const float*)d_in[1];
    const float* cw     = (const float*)d_in[2];
    const float* cb     = (const float*)d_in[3];
    const float* W_x    = (const float*)d_in[4];
    const float* W_dt   = (const float*)d_in[5];
    const float* b_dt   = (const float*)d_in[6];
    const float* A_log  = (const float*)d_in[7];
    const float* D_skip = (const float*)d_in[8];
    const float* W_out  = (const float*)d_in[9];
    float* out = (float*)d_out;

    // fp32 workspace (identical 204.5MB footprint to rounds 2-6):
    const size_t MMDI = (size_t)MM * DI;
    float* xi  = (float*)d_ws;          // xz-half -> Wx-split -> dt -> Wout-split
    float* zb  = xi  + MMDI;            // z -> y (in-place)
    float* xcb = zb  + MMDI;            // x/Win splits -> xc split pair -> y splits
    float* xdb = xcb + MMDI;            // MM*96

    // f16 aliases (all inside dead fp32 regions at their time of use)
    _Float16* xh   = (_Float16*)xcb;                 // MM*DM
    _Float16* xl   = xh + (size_t)MM * DM;
    _Float16* Winh = xl + (size_t)MM * DM;           // 2*DI*DM
    _Float16* Winl = Winh + (size_t)2 * DI * DM;
    _Float16* xch  = (_Float16*)xcb;                 // MM*DI (conv out)
    _Float16* xcl  = xch + MMDI;
    _Float16* Wxh  = (_Float16*)xi;                  // 96*DI (post-conv dead window)
    _Float16* Wxl  = Wxh + (size_t)96 * DI;
    _Float16* yh   = (_Float16*)xcb;                 // MM*DI (after scan)
    _Float16* yl   = yh + MMDI;
    _Float16* Woh  = (_Float16*)xi;                  // DM*DI (after scan)
    _Float16* Wol  = Woh + (size_t)DM * DI;

    const dim3 blk(256);

    // split inputs of GEMM1
    split_kernel<<<dim3((MM * DM / 4) / 256), blk, 0, stream>>>(x, xh, xl, MM * DM / 4);
    split_kernel<<<dim3((2 * DI * DM / 4) / 256), blk, 0, stream>>>(
        W_in, Winh, Winl, 2 * DI * DM / 4);

    // xz = x @ W_in^T, xi / z halves (MFMA split GEMM, gload_lds staging)
    gemm_nt_split<<<dim3(DI / 128, MM / 128), blk, 0, stream>>>(
        xi, xh, xl, Winh, Winl, MM, DI, DM);
    gemm_nt_split<<<dim3(DI / 128, MM / 128), blk, 0, stream>>>(
        zb, xh, xl, Winh + (size_t)DI * DM, Winl + (size_t)DI * DM, MM, DI, DM);

    // conv overwrites xcb with split-f16 xc
    conv_silu_split_kernel<<<dim3(MM * (DI / 4) / 256), blk, 0, stream>>>(
        xi, cw, cb, xch, xcl);

    // W_x split into xi slab (dead between conv and dt)
    split_kernel<<<dim3((96 * DI / 4) / 256), blk, 0, stream>>>(
        W_x, Wxh, Wxl, 96 * DI / 4);

    xdbl_mfma_kernel<<<dim3(MM / 64), blk, 0, stream>>>(xch, xcl, Wxh, Wxl, xdb);

    // dt via split-MFMA (reads xdbl cols 0..63 + W_dt directly; writes xi)
    dt_mfma_kernel<<<dim3(DI / 128, MM / 128), blk, 0, stream>>>(
        xdb, W_dt, b_dt, xi);

    scan_kernel<<<dim3(BB * DI / 16), blk, 0, stream>>>(
        xi, xch, xcl, xdb, zb, A_log, D_skip, zb);

    // split GEMM4 inputs into now-dead regions
    split_kernel<<<dim3((MM * DI / 4) / 256), blk, 0, stream>>>(zb, yh, yl, MM * DI / 4);
    split_kernel<<<dim3((DM * DI / 4) / 256), blk, 0, stream>>>(
        W_out, Woh, Wol, DM * DI / 4);

    gemm_nt_split<<<dim3(DM / 128, MM / 128), blk, 0, stream>>>(
        out, yh, yl, Woh, Wol, MM, DM, DI);
}

// Round 8
// 762.832 us; speedup vs baseline: 2.8651x; 1.0342x over previous
//
#include <hip/hip_runtime.h>
#include <hip/hip_bf16.h>

// Problem constants (match reference)
#define DM    1024   // D_MODEL
#define DI    2048   // D_INNER
#define DCONV 4
#define DSTATE 16
#define DRANK 64
#define BB    4
#define LSEQ  2048
#define MM    (BB*LSEQ)   // 8192 rows
#define CHUNK 64          // scan LDS-staging chunk (timesteps)

typedef _Float16 f16x8 __attribute__((ext_vector_type(8)));
typedef _Float16 f16x4 __attribute__((ext_vector_type(4)));
typedef float    f32x4 __attribute__((ext_vector_type(4)));

// LDS swizzle: 16B slot within a 64B row, XOR'd so 16-row column reads are
// 2-way (free). global_load_lds writes linearly, so the write side achieves
// the same permutation via pre-swizzled per-lane GLOBAL source addresses
// (linear dest + inverse-swz source + swz read; XOR is its own inverse).
#define SWIZMASK(row) (((row) & 3) ^ (((row) >> 2) & 1))
#define SWIZ(row, g)  ((((row) * 4) + ((g) ^ SWIZMASK(row))) * 8)

#define GLOAD_LDS16(gp, sp) __builtin_amdgcn_global_load_lds( \
    (const __attribute__((address_space(1))) void*)(gp),      \
    (__attribute__((address_space(3))) void*)(sp), 16, 0, 0)

// ---------------------------------------------------------------------------
// split: fp32 -> (hi, lo) f16 pair.  lo = f16(x - float(hi)); x==hi+lo+O(2^-22)
// ---------------------------------------------------------------------------
__global__ __launch_bounds__(256) void split_kernel(
    const float* __restrict__ in, _Float16* __restrict__ hi,
    _Float16* __restrict__ lo, int n4)
{
    const int i = blockIdx.x * 256 + threadIdx.x;
    if (i >= n4) return;
    const float4 v = ((const float4*)in)[i];
    _Float16 h[4], l[4];
    h[0] = (_Float16)v.x; l[0] = (_Float16)(v.x - (float)h[0]);
    h[1] = (_Float16)v.y; l[1] = (_Float16)(v.y - (float)h[1]);
    h[2] = (_Float16)v.z; l[2] = (_Float16)(v.z - (float)h[2]);
    h[3] = (_Float16)v.w; l[3] = (_Float16)(v.w - (float)h[3]);
    *(uint2*)&hi[(size_t)i * 4] = *(uint2*)h;
    *(uint2*)&lo[(size_t)i * 4] = *(uint2*)l;
}

// ---------------------------------------------------------------------------
// Split-precision MFMA GEMM NT, global_load_lds staging (unchanged, passing).
// ---------------------------------------------------------------------------
__global__ __launch_bounds__(256) void gemm_nt_split(
    float* __restrict__ C,
    const _Float16* __restrict__ Ah, const _Float16* __restrict__ Al,
    const _Float16* __restrict__ Bh, const _Float16* __restrict__ Bl,
    int M, int N, int K)
{
    __shared__ __align__(16) _Float16 sAh[128 * 32];
    __shared__ __align__(16) _Float16 sAl[128 * 32];
    __shared__ __align__(16) _Float16 sBh[128 * 32];
    __shared__ __align__(16) _Float16 sBl[128 * 32];

    const int t = threadIdx.x;
    const int m0 = blockIdx.y * 128, n0 = blockIdx.x * 128;
    const int l = t & 63, w = t >> 6;
    const int wr = w >> 1, wc = w & 1;
    const int fr = l & 15, fg = l >> 4;

    f32x4 acc[4][4];
    const f32x4 zz = {0.f, 0.f, 0.f, 0.f};
#pragma unroll
    for (int i = 0; i < 4; ++i)
#pragma unroll
        for (int j = 0; j < 4; ++j) acc[i][j] = zz;

    const int ch0 = w * 2, ch1 = w * 2 + 1;
    const int g4 = l & 3;
    const int rA0 = ch0 * 16 + (l >> 2), rA1 = ch1 * 16 + (l >> 2);
    const int c0 = (g4 ^ SWIZMASK(rA0)) * 8, c1 = (g4 ^ SWIZMASK(rA1)) * 8;
    const size_t gA0 = (size_t)(m0 + rA0) * K + c0;
    const size_t gA1 = (size_t)(m0 + rA1) * K + c1;
    const size_t gB0 = (size_t)(n0 + rA0) * K + c0;
    const size_t gB1 = (size_t)(n0 + rA1) * K + c1;
    const int lo0 = ch0 * 512, lo1 = ch1 * 512;

    const int nk = K / 32;
    for (int kt = 0; kt < nk; ++kt) {
        const size_t ko = (size_t)kt * 32;
        GLOAD_LDS16(&Ah[gA0 + ko], &sAh[lo0]);
        GLOAD_LDS16(&Ah[gA1 + ko], &sAh[lo1]);
        GLOAD_LDS16(&Al[gA0 + ko], &sAl[lo0]);
        GLOAD_LDS16(&Al[gA1 + ko], &sAl[lo1]);
        GLOAD_LDS16(&Bh[gB0 + ko], &sBh[lo0]);
        GLOAD_LDS16(&Bh[gB1 + ko], &sBh[lo1]);
        GLOAD_LDS16(&Bl[gB0 + ko], &sBl[lo0]);
        GLOAD_LDS16(&Bl[gB1 + ko], &sBl[lo1]);
        __syncthreads();

        f16x8 fbh[4], fbl[4];
#pragma unroll
        for (int nr = 0; nr < 4; ++nr) {
            const int row = wc * 64 + nr * 16 + fr;
            const int ad = SWIZ(row, fg);
            fbh[nr] = *(const f16x8*)&sBh[ad];
            fbl[nr] = *(const f16x8*)&sBl[ad];
        }
#pragma unroll
        for (int mr = 0; mr < 4; ++mr) {
            const int row = wr * 64 + mr * 16 + fr;
            const int ad = SWIZ(row, fg);
            const f16x8 fah = *(const f16x8*)&sAh[ad];
            const f16x8 fal = *(const f16x8*)&sAl[ad];
#pragma unroll
            for (int nr = 0; nr < 4; ++nr) {
                acc[mr][nr] = __builtin_amdgcn_mfma_f32_16x16x32_f16(
                    fah, fbh[nr], acc[mr][nr], 0, 0, 0);
                acc[mr][nr] = __builtin_amdgcn_mfma_f32_16x16x32_f16(
                    fah, fbl[nr], acc[mr][nr], 0, 0, 0);
                acc[mr][nr] = __builtin_amdgcn_mfma_f32_16x16x32_f16(
                    fal, fbh[nr], acc[mr][nr], 0, 0, 0);
            }
        }
        __syncthreads();
    }

#pragma unroll
    for (int mr = 0; mr < 4; ++mr)
#pragma unroll
        for (int nr = 0; nr < 4; ++nr) {
            const int col = n0 + wc * 64 + nr * 16 + fr;
#pragma unroll
            for (int q = 0; q < 4; ++q) {
                const int rowc = m0 + wr * 64 + mr * 16 + fg * 4 + q;
                C[(size_t)rowc * N + col] = acc[mr][nr][q];
            }
        }
}

// ---------------------------------------------------------------------------
// dt[M][2048] = softplus(xdbl[:, :64] * W_dt[2048][64]^T + b_dt)  (unchanged)
// ---------------------------------------------------------------------------
__global__ __launch_bounds__(256) void dt_mfma_kernel(
    const float* __restrict__ xdbl, const float* __restrict__ Wdt,
    const float* __restrict__ bdt, float* __restrict__ dtout)
{
    __shared__ __align__(16) _Float16 sAh[128 * 32];
    __shared__ __align__(16) _Float16 sAl[128 * 32];
    __shared__ __align__(16) _Float16 sBh[128 * 32];
    __shared__ __align__(16) _Float16 sBl[128 * 32];

    const int t = threadIdx.x;
    const int m0 = blockIdx.y * 128, n0 = blockIdx.x * 128;
    const int l = t & 63, w = t >> 6;
    const int wr = w >> 1, wc = w & 1;
    const int fr = l & 15, fg = l >> 4;

    f32x4 acc[4][4];
    const f32x4 zz = {0.f, 0.f, 0.f, 0.f};
#pragma unroll
    for (int i = 0; i < 4; ++i)
#pragma unroll
        for (int j = 0; j < 4; ++j) acc[i][j] = zz;

#pragma unroll
    for (int kt = 0; kt < 2; ++kt) {
        __syncthreads();
#pragma unroll
        for (int ss = 0; ss < 2; ++ss) {
            const int s = t + ss * 256;
            const int row = s >> 2, c = s & 3;
            const int dst = SWIZ(row, c);
            {
                const float* p = &xdbl[(size_t)(m0 + row) * 96 + kt * 32 + c * 8];
                const float4 a0 = *(const float4*)p, a1 = *(const float4*)(p + 4);
                _Float16 h[8], lo8[8];
                const float vv[8] = {a0.x,a0.y,a0.z,a0.w,a1.x,a1.y,a1.z,a1.w};
#pragma unroll
                for (int q = 0; q < 8; ++q) {
                    h[q] = (_Float16)vv[q]; lo8[q] = (_Float16)(vv[q] - (float)h[q]);
                }
                *(uint4*)&sAh[dst] = *(uint4*)h;
                *(uint4*)&sAl[dst] = *(uint4*)lo8;
            }
            {
                const float* p = &Wdt[(size_t)(n0 + row) * 64 + kt * 32 + c * 8];
                const float4 b0 = *(const float4*)p, b1 = *(const float4*)(p + 4);
                _Float16 h[8], lo8[8];
                const float vv[8] = {b0.x,b0.y,b0.z,b0.w,b1.x,b1.y,b1.z,b1.w};
#pragma unroll
                for (int q = 0; q < 8; ++q) {
                    h[q] = (_Float16)vv[q]; lo8[q] = (_Float16)(vv[q] - (float)h[q]);
                }
                *(uint4*)&sBh[dst] = *(uint4*)h;
                *(uint4*)&sBl[dst] = *(uint4*)lo8;
            }
        }
        __syncthreads();

        f16x8 fbh[4], fbl[4];
#pragma unroll
        for (int nr = 0; nr < 4; ++nr) {
            const int row = wc * 64 + nr * 16 + fr;
            const int ad = SWIZ(row, fg);
            fbh[nr] = *(const f16x8*)&sBh[ad];
            fbl[nr] = *(const f16x8*)&sBl[ad];
        }
#pragma unroll
        for (int mr = 0; mr < 4; ++mr) {
            const int row = wr * 64 + mr * 16 + fr;
            const int ad = SWIZ(row, fg);
            const f16x8 fah = *(const f16x8*)&sAh[ad];
            const f16x8 fal = *(const f16x8*)&sAl[ad];
#pragma unroll
            for (int nr = 0; nr < 4; ++nr) {
                acc[mr][nr] = __builtin_amdgcn_mfma_f32_16x16x32_f16(
                    fah, fbh[nr], acc[mr][nr], 0, 0, 0);
                acc[mr][nr] = __builtin_amdgcn_mfma_f32_16x16x32_f16(
                    fah, fbl[nr], acc[mr][nr], 0, 0, 0);
                acc[mr][nr] = __builtin_amdgcn_mfma_f32_16x16x32_f16(
                    fal, fbh[nr], acc[mr][nr], 0, 0, 0);
            }
        }
    }

#pragma unroll
    for (int mr = 0; mr < 4; ++mr)
#pragma unroll
        for (int nr = 0; nr < 4; ++nr) {
            const int col = n0 + wc * 64 + nr * 16 + fr;
            const float bd = bdt[col];
#pragma unroll
            for (int q = 0; q < 4; ++q) {
                const int rowc = m0 + wr * 64 + mr * 16 + fg * 4 + q;
                const float v = acc[mr][nr][q] + bd;
                dtout[(size_t)rowc * DI + col] =
                    (v > 20.f) ? v : log1pf(__expf(v));
            }
        }
}

// ---------------------------------------------------------------------------
// Depthwise causal conv (width 4) + bias + SiLU; emits xc as split f16 pair.
// ---------------------------------------------------------------------------
__global__ __launch_bounds__(256) void conv_silu_split_kernel(
    const float* __restrict__ xi, const float* __restrict__ cw,
    const float* __restrict__ cb, _Float16* __restrict__ xch,
    _Float16* __restrict__ xcl)
{
    const int idx = blockIdx.x * 256 + threadIdx.x;   // over MM*DI/4
    const int d4 = idx & (DI / 4 - 1);
    const int bl = idx / (DI / 4);
    const int l  = bl & (LSEQ - 1);
    const int d  = d4 * 4;

    float4 acc = *(const float4*)&cb[d];
    const float4 w0 = *(const float4*)&cw[(d + 0) * 4];
    const float4 w1 = *(const float4*)&cw[(d + 1) * 4];
    const float4 w2 = *(const float4*)&cw[(d + 2) * 4];
    const float4 w3 = *(const float4*)&cw[(d + 3) * 4];

#pragma unroll
    for (int k = 0; k < 4; ++k) {
        const int ll = l - 3 + k;
        if (ll < 0) continue;
        const float4 xv = *(const float4*)&xi[(size_t)(bl - 3 + k) * DI + d];
        const float wk0 = (k == 0) ? w0.x : (k == 1) ? w0.y : (k == 2) ? w0.z : w0.w;
        const float wk1 = (k == 0) ? w1.x : (k == 1) ? w1.y : (k == 2) ? w1.z : w1.w;
        const float wk2 = (k == 0) ? w2.x : (k == 1) ? w2.y : (k == 2) ? w2.z : w2.w;
        const float wk3 = (k == 0) ? w3.x : (k == 1) ? w3.y : (k == 2) ? w3.z : w3.w;
        acc.x = fmaf(xv.x, wk0, acc.x);
        acc.y = fmaf(xv.y, wk1, acc.y);
        acc.z = fmaf(xv.z, wk2, acc.z);
        acc.w = fmaf(xv.w, wk3, acc.w);
    }
    acc.x = acc.x / (1.f + __expf(-acc.x));
    acc.y = acc.y / (1.f + __expf(-acc.y));
    acc.z = acc.z / (1.f + __expf(-acc.z));
    acc.w = acc.w / (1.f + __expf(-acc.w));

    _Float16 h[4], lo4[4];
    h[0] = (_Float16)acc.x; lo4[0] = (_Float16)(acc.x - (float)h[0]);
    h[1] = (_Float16)acc.y; lo4[1] = (_Float16)(acc.y - (float)h[1]);
    h[2] = (_Float16)acc.z; lo4[2] = (_Float16)(acc.z - (float)h[2]);
    h[3] = (_Float16)acc.w; lo4[3] = (_Float16)(acc.w - (float)h[3]);
    *(uint2*)&xch[(size_t)bl * DI + d] = *(uint2*)h;
    *(uint2*)&xcl[(size_t)bl * DI + d] = *(uint2*)lo4;
}

// ---------------------------------------------------------------------------
// xdbl[M][96] = (Xh+Xl)[M][2048] * ((Wh+Wl)[96][2048])^T  (unchanged)
// ---------------------------------------------------------------------------
__global__ __launch_bounds__(256) void xdbl_mfma_kernel(
    const _Float16* __restrict__ Xh, const _Float16* __restrict__ Xl,
    const _Float16* __restrict__ Wh, const _Float16* __restrict__ Wl,
    float* __restrict__ xdbl)
{
    __shared__ __align__(16) _Float16 sXh[64 * 32];
    __shared__ __align__(16) _Float16 sXl[64 * 32];
    __shared__ __align__(16) _Float16 sWh[96 * 32];
    __shared__ __align__(16) _Float16 sWl[96 * 32];

    const int t = threadIdx.x;
    const int m0 = blockIdx.x * 64;
    const int l = t & 63, w = t >> 6;
    const int fr = l & 15, fg = l >> 4;

    f32x4 acc[6];
    const f32x4 zz = {0.f, 0.f, 0.f, 0.f};
#pragma unroll
    for (int i = 0; i < 6; ++i) acc[i] = zz;

    const int ar = t >> 2, ac = t & 3;
    const int da = SWIZ(ar, ac);
    const size_t gX = (size_t)(m0 + ar) * DI + ac * 8;
    const int br0 = t >> 2, bc0 = t & 3;
    const int db0 = SWIZ(br0, bc0);
    const size_t gW0 = (size_t)br0 * DI + bc0 * 8;
    const bool has1 = t < 128;
    const int br1 = (t + 256) >> 2, bc1 = t & 3;
    const int db1 = SWIZ(br1, bc1);
    const size_t gW1 = (size_t)br1 * DI + bc1 * 8;

    uint4 vXh = *(const uint4*)&Xh[gX], vXl = *(const uint4*)&Xl[gX];
    uint4 vWh0 = *(const uint4*)&Wh[gW0], vWl0 = *(const uint4*)&Wl[gW0];
    uint4 vWh1, vWl1;
    if (has1) { vWh1 = *(const uint4*)&Wh[gW1]; vWl1 = *(const uint4*)&Wl[gW1]; }

    const int nk = DI / 32;
    for (int kt = 0; kt < nk; ++kt) {
        __syncthreads();
        *(uint4*)&sXh[da] = vXh;   *(uint4*)&sXl[da] = vXl;
        *(uint4*)&sWh[db0] = vWh0; *(uint4*)&sWl[db0] = vWl0;
        if (has1) { *(uint4*)&sWh[db1] = vWh1; *(uint4*)&sWl[db1] = vWl1; }
        __syncthreads();

        if (kt + 1 < nk) {
            const size_t o = (size_t)(kt + 1) * 32;
            vXh = *(const uint4*)&Xh[gX + o];   vXl = *(const uint4*)&Xl[gX + o];
            vWh0 = *(const uint4*)&Wh[gW0 + o]; vWl0 = *(const uint4*)&Wl[gW0 + o];
            if (has1) { vWh1 = *(const uint4*)&Wh[gW1 + o]; vWl1 = *(const uint4*)&Wl[gW1 + o]; }
        }

        const int aad = SWIZ(w * 16 + fr, fg);
        const f16x8 fah = *(const f16x8*)&sXh[aad];
        const f16x8 fal = *(const f16x8*)&sXl[aad];
#pragma unroll
        for (int nr = 0; nr < 6; ++nr) {
            const int bad = SWIZ(nr * 16 + fr, fg);
            const f16x8 fbh = *(const f16x8*)&sWh[bad];
            const f16x8 fbl = *(const f16x8*)&sWl[bad];
            acc[nr] = __builtin_amdgcn_mfma_f32_16x16x32_f16(fah, fbh, acc[nr], 0, 0, 0);
            acc[nr] = __builtin_amdgcn_mfma_f32_16x16x32_f16(fah, fbl, acc[nr], 0, 0, 0);
            acc[nr] = __builtin_amdgcn_mfma_f32_16x16x32_f16(fal, fbh, acc[nr], 0, 0, 0);
        }
    }

#pragma unroll
    for (int nr = 0; nr < 6; ++nr) {
        const int col = nr * 16 + fr;
#pragma unroll
        for (int q = 0; q < 4; ++q) {
            const int row = m0 + w * 16 + fg * 4 + q;
            xdbl[(size_t)row * 96 + col] = acc[nr][q];
        }
    }
}

// ---------------------------------------------------------------------------
// Selective scan, instruction-minimized hot loop:
//  - s_du[j][g] = {dt, dt*xc}  (one b64 broadcast read; u-product staged once)
//  - s_bc[j][s] = {B, C}       (one b64 read)
//  - per step: 2 ds_read_b64 + mul/exp/mul/fma/mul + 1 ds_write_b32
//  - emits y directly as split f16 pair (yh/yl alias xch/xcl; per-row
//    read-before-write ordering holds: chunk ch rows are read one chunk
//    before they are written; NO __restrict__ on the aliasing params)
// ---------------------------------------------------------------------------
__global__ __launch_bounds__(256) void scan_kernel(
    const float* __restrict__ dt,
    const _Float16* xch, const _Float16* xcl,
    const float* __restrict__ xdbl, const float* __restrict__ z,
    const float* __restrict__ A_log, const float* __restrict__ D_skip,
    _Float16* yh, _Float16* yl)
{
    __shared__ float s_du[CHUNK][16][2];   // {dt, dt*xc}
    __shared__ float s_bc[CHUNK][16][2];   // {B, C}
    __shared__ float s_xc[CHUNK][20];      // xc for D-term (padded)
    __shared__ float s_z [CHUNK][20];      // z in, y out (padded)
    __shared__ float s_p [16][16][17];
    __shared__ float s_D [16];

    const int t = threadIdx.x;
    const int g = t >> 4;             // channel in block
    const int s = t & 15;             // state index
    const int c = blockIdx.x * 16 + g;
    const int b = c >> 11;
    const int d = c & (DI - 1);
    const int d0 = (blockIdx.x * 16) & (DI - 1);

    const int lr = t >> 2;            // stager row 0..63
    const int lc = t & 3;             // stager float4-col

    if (t < 16) s_D[t] = D_skip[d0 + t];

    const float Acoef = -__expf(A_log[d * DSTATE + s]);
    const size_t rbase = (size_t)b * LSEQ;

    float h = 0.f;
    float4 r_dt, r_z, r_B, r_C;
    f16x4 r_xh, r_xl;

    {   // prologue: chunk 0 -> regs
        const size_t row = rbase + lr;
        r_dt = *(const float4*)&dt[row * DI + d0 + lc * 4];
        r_xh = *(const f16x4*)&xch[row * DI + d0 + lc * 4];
        r_xl = *(const f16x4*)&xcl[row * DI + d0 + lc * 4];
        r_z  = *(const float4*)&z [row * DI + d0 + lc * 4];
        r_B  = *(const float4*)&xdbl[row * 96 + DRANK + lc * 4];
        r_C  = *(const float4*)&xdbl[row * 96 + DRANK + DSTATE + lc * 4];
    }

    for (int ch = 0; ch < LSEQ / CHUNK; ++ch) {
        __syncthreads();              // prev chunk LDS fully consumed/stored
        {
            float xf[4];
            xf[0] = (float)r_xh[0] + (float)r_xl[0];
            xf[1] = (float)r_xh[1] + (float)r_xl[1];
            xf[2] = (float)r_xh[2] + (float)r_xl[2];
            xf[3] = (float)r_xh[3] + (float)r_xl[3];
            const float dtv[4] = {r_dt.x, r_dt.y, r_dt.z, r_dt.w};
            const float Bv[4]  = {r_B.x, r_B.y, r_B.z, r_B.w};
            const float Cv[4]  = {r_C.x, r_C.y, r_C.z, r_C.w};
#pragma unroll
            for (int i = 0; i < 4; ++i) {
                float2 du = {dtv[i], dtv[i] * xf[i]};
                *(float2*)&s_du[lr][lc * 4 + i][0] = du;
                float2 bc = {Bv[i], Cv[i]};
                *(float2*)&s_bc[lr][lc * 4 + i][0] = bc;
            }
            *(float4*)&s_xc[lr][lc * 4] = *(float4*)xf;
            *(float4*)&s_z [lr][lc * 4] = r_z;
        }
        __syncthreads();

        if (ch + 1 < LSEQ / CHUNK) {  // prefetch next chunk (stays in flight)
            const size_t row = rbase + (size_t)(ch + 1) * CHUNK + lr;
            r_dt = *(const float4*)&dt[row * DI + d0 + lc * 4];
            r_xh = *(const f16x4*)&xch[row * DI + d0 + lc * 4];
            r_xl = *(const f16x4*)&xcl[row * DI + d0 + lc * 4];
            r_z  = *(const float4*)&z [row * DI + d0 + lc * 4];
            r_B  = *(const float4*)&xdbl[row * 96 + DRANK + lc * 4];
            r_C  = *(const float4*)&xdbl[row * 96 + DRANK + DSTATE + lc * 4];
        }

#pragma unroll
        for (int sub = 0; sub < CHUNK / 16; ++sub) {
            const int base = sub * 16;
#pragma unroll
            for (int j = 0; j < 16; ++j) {
                const float2 du = *(const float2*)&s_du[base + j][g][0];
                const float2 bc = *(const float2*)&s_bc[base + j][s][0];
                const float dA = __expf(du.x * Acoef);
                h = fmaf(dA, h, du.y * bc.x);
                s_p[g][j][s] = h * bc.y;
            }
            __syncthreads();
            float accp = 0.f;
#pragma unroll
            for (int k = 0; k < 16; ++k)
                accp += s_p[g][s][k];
            {
                const int row = base + s;
                const float xv = s_xc[row][g];
                const float zv = s_z [row][g];
                const float sig = 1.f / (1.f + __expf(-zv));
                s_z[row][g] = fmaf(xv, s_D[g], accp) * (zv * sig);
            }
            __syncthreads();
        }
        // y chunk store as split f16 pair (in-place over xch/xcl rows of this
        // chunk -- those rows were consumed a full chunk ago)
        {
            const size_t row = rbase + (size_t)ch * CHUNK + lr;
            const float4 yv = *(const float4*)&s_z[lr][lc * 4];
            _Float16 hh[4], ll[4];
            const float vv[4] = {yv.x, yv.y, yv.z, yv.w};
#pragma unroll
            for (int q = 0; q < 4; ++q) {
                hh[q] = (_Float16)vv[q];
                ll[q] = (_Float16)(vv[q] - (float)hh[q]);
            }
            *(uint2*)&yh[row * DI + d0 + lc * 4] = *(uint2*)hh;
            *(uint2*)&yl[row * DI + d0 + lc * 4] = *(uint2*)ll;
        }
    }
}

// ---------------------------------------------------------------------------
extern "C" void kernel_launch(void* const* d_in, const int* in_sizes, int n_in,
                              void* d_out, int out_size, void* d_ws, size_t ws_size,
                              hipStream_t stream)
{
    const float* x      = (const float*)d_in[0];
    const float* W_in   = (const float*)d_in[1];
    const float* cw     = (const float*)d_in[2];
    const float* cb     = (const float*)d_in[3];
    const float* W_x    = (const float*)d_in[4];
    const float* W_dt   = (const float*)d_in[5];
    const float* b_dt   = (const float*)d_in[6];
    const float* A_log  = (const float*)d_in[7];
    const float* D_skip = (const float*)d_in[8];
    const float* W_out  = (const float*)d_in[9];
    float* out = (float*)d_out;

    // fp32 workspace (identical 204.5MB footprint):
    const size_t MMDI = (size_t)MM * DI;
    float* xi  = (float*)d_ws;          // xz-half -> Wx-split -> dt -> Wout-split
    float* zb  = xi  + MMDI;            // z (read-only after GEMM1)
    float* xcb = zb  + MMDI;            // x/Win splits -> xc split pair -> y splits
    float* xdb = xcb + MMDI;            // MM*96

    // f16 aliases (all inside dead fp32 regions at their time of use)
    _Float16* xh   = (_Float16*)xcb;                 // MM*DM
    _Float16* xl   = xh + (size_t)MM * DM;
    _Float16* Winh = xl + (size_t)MM * DM;           // 2*DI*DM
    _Float16* Winl = Winh + (size_t)2 * DI * DM;
    _Float16* xch  = (_Float16*)xcb;                 // MM*DI (conv out)
    _Float16* xcl  = xch + MMDI;
    _Float16* Wxh  = (_Float16*)xi;                  // 96*DI (post-conv dead window)
    _Float16* Wxl  = Wxh + (size_t)96 * DI;
    _Float16* yh   = (_Float16*)xcb;                 // MM*DI (scan writes in-place)
    _Float16* yl   = yh + MMDI;
    _Float16* Woh  = (_Float16*)xi;                  // DM*DI (after scan? see note)
    _Float16* Wol  = Woh + (size_t)DM * DI;

    const dim3 blk(256);

    // split inputs of GEMM1
    split_kernel<<<dim3((MM * DM / 4) / 256), blk, 0, stream>>>(x, xh, xl, MM * DM / 4);
    split_kernel<<<dim3((2 * DI * DM / 4) / 256), blk, 0, stream>>>(
        W_in, Winh, Winl, 2 * DI * DM / 4);

    // xz = x @ W_in^T, xi / z halves (MFMA split GEMM, gload_lds staging)
    gemm_nt_split<<<dim3(DI / 128, MM / 128), blk, 0, stream>>>(
        xi, xh, xl, Winh, Winl, MM, DI, DM);
    gemm_nt_split<<<dim3(DI / 128, MM / 128), blk, 0, stream>>>(
        zb, xh, xl, Winh + (size_t)DI * DM, Winl + (size_t)DI * DM, MM, DI, DM);

    // conv overwrites xcb with split-f16 xc
    conv_silu_split_kernel<<<dim3(MM * (DI / 4) / 256), blk, 0, stream>>>(
        xi, cw, cb, xch, xcl);

    // W_x split into xi slab (dead between conv and dt)
    split_kernel<<<dim3((96 * DI / 4) / 256), blk, 0, stream>>>(
        W_x, Wxh, Wxl, 96 * DI / 4);

    xdbl_mfma_kernel<<<dim3(MM / 64), blk, 0, stream>>>(xch, xcl, Wxh, Wxl, xdb);

    // dt via split-MFMA (writes xi; Wx splits consumed already)
    dt_mfma_kernel<<<dim3(DI / 128, MM / 128), blk, 0, stream>>>(
        xdb, W_dt, b_dt, xi);

    // W_out split into the tail of the xi slab (dt occupies the first
    // MM*DI floats? no -- dt IS the whole xi slab; put Wout split in zb tail?
    // zb is still needed (scan reads z). Use the xdb tail: xdb slab is MM*96
    // floats = 3.1MB; Wout split needs DM*DI*2*2B = 8.4MB. Instead reuse the
    // Winh region inside xcb? xcb now holds xch/xcl (needed). Safe dead slot:
    // after scan, xi (dt) is dead -> split W_out AFTER scan into xi.
    scan_kernel<<<dim3(BB * DI / 16), blk, 0, stream>>>(
        xi, xch, xcl, xdb, zb, A_log, D_skip, yh, yl);

    split_kernel<<<dim3((DM * DI / 4) / 256), blk, 0, stream>>>(
        W_out, Woh, Wol, DM * DI / 4);

    gemm_nt_split<<<dim3(DM / 128, MM / 128), blk, 0, stream>>>(
        out, yh, yl, Woh, Wol, MM, DM, DI);
}